// Round 1
// baseline (3835.903 us; speedup 1.0000x reference)
//
#include <hip/hip_runtime.h>

#define NN 2048      // points
#define NB 16        // batch
#define KK 20        // k neighbors
#define EPSF 1e-5f

typedef unsigned long long ull;

__device__ __forceinline__ float shflx_f(float v, int m) { return __shfl_xor(v, m, 64); }
__device__ __forceinline__ ull shflx_u64(ull v, int m) {
  int lo = __shfl_xor((int)(unsigned)v, m, 64);
  int hi = __shfl_xor((int)(unsigned)(v >> 32), m, 64);
  return (((ull)(unsigned)hi) << 32) | (unsigned)lo;
}

// ---------------- squared norms ----------------
__global__ __launch_bounds__(256) void xx_kernel(const float* __restrict__ x,
    float* __restrict__ xx, int C, long bstride) {
  const int b = blockIdx.y;
  const int n = blockIdx.x * 256 + threadIdx.x;
  const float* xb = x + (size_t)b * bstride;
  float s = 0.f;
  for (int c = 0; c < C; c++) { float v = xb[(size_t)c * NN + n]; s = fmaf(v, v, s); }
  xx[b * NN + n] = s;
}

// ---------------- kNN: 16 queries/block (4 per wave), exact top-20 ----------------
// score(i,j) = dot(x_i,x_j) - 0.5*||x_j||^2  (same ordering as reference pd)
__global__ __launch_bounds__(256) void knn_kernel(const float* __restrict__ xin,
    const float* __restrict__ xxg, int* __restrict__ idxout, int C, long bstride)
{
  __shared__ __align__(16) float xr[8 * NN];   // staged candidate rows; reused as top-k buffers
  __shared__ float xq[16 * 128];               // 16 query vectors
  const int t = threadIdx.x;
  const int lane = t & 63;
  const int wave = t >> 6;
  const int b = blockIdx.y;
  const int q0 = blockIdx.x * 16;
  const float* xb = xin + (size_t)b * bstride;

  for (int i = t; i < 16 * C; i += 256) {
    int q = i / C, c = i - q * C;
    xq[q * 128 + c] = xb[(size_t)c * NN + q0 + q];
  }

  float acc[4][32];
#pragma unroll
  for (int q = 0; q < 4; q++)
#pragma unroll
    for (int jj = 0; jj < 32; jj++) acc[q][jj] = 0.f;

  const int swz = (lane & 7) << 2;   // XOR swizzle -> conflict-free ds_read_b128
  const int jbase = lane << 5;       // lane owns candidates [32*lane, 32*lane+32)

  for (int cc = 0; cc < C; cc += 8) {
    const int nr = (C - cc) < 8 ? (C - cc) : 8;
    __syncthreads();
    for (int r = 0; r < nr; r++) {
      const float* src = xb + (size_t)(cc + r) * NN;
      for (int i = t; i < NN; i += 256) {
        int phys = (i & ~31) | ((i & 31) ^ ((i >> 3) & 28));
        xr[r * NN + phys] = src[i];
      }
    }
    __syncthreads();
    for (int r = 0; r < nr; r++) {
      float qv[4];
#pragma unroll
      for (int q = 0; q < 4; q++) qv[q] = xq[(wave * 4 + q) * 128 + cc + r];
#pragma unroll
      for (int u = 0; u < 8; u++) {
        const float4 xv = *(const float4*)&xr[r * NN + jbase + ((u << 2) ^ swz)];
#pragma unroll
        for (int q = 0; q < 4; q++) {
          acc[q][4 * u + 0] = fmaf(qv[q], xv.x, acc[q][4 * u + 0]);
          acc[q][4 * u + 1] = fmaf(qv[q], xv.y, acc[q][4 * u + 1]);
          acc[q][4 * u + 2] = fmaf(qv[q], xv.z, acc[q][4 * u + 2]);
          acc[q][4 * u + 3] = fmaf(qv[q], xv.w, acc[q][4 * u + 3]);
        }
      }
    }
  }
  __syncthreads();  // everyone done with xr -> reuse as top-k buffers

  // scores = acc - 0.5*xx[j]
  {
    const float* xxb = xxg + b * NN;
#pragma unroll
    for (int u = 0; u < 8; u++) {
      const float4 xv = *(const float4*)&xxb[jbase + 4 * u];
#pragma unroll
      for (int q = 0; q < 4; q++) {
        acc[q][4 * u + 0] -= 0.5f * xv.x;
        acc[q][4 * u + 1] -= 0.5f * xv.y;
        acc[q][4 * u + 2] -= 0.5f * xv.z;
        acc[q][4 * u + 3] -= 0.5f * xv.w;
      }
    }
  }

  ull* buf = ((ull*)xr) + wave * 2048;   // 16KB per wave

#pragma unroll
  for (int q = 0; q < 4; q++) {
    // lane-local max
    float lm = acc[q][0];
#pragma unroll
    for (int jj = 1; jj < 32; jj++) lm = fmaxf(lm, acc[q][jj]);
    // bitonic sort of 64 lane-maxima (descending); tau = rank-19 value.
    // Guarantee: at most 19 values exceed the true 20th-largest, so at most 19
    // lane-maxima exceed it -> tau <= t20 -> filter "v >= tau" keeps all top-20.
    float sv = lm;
#pragma unroll
    for (int kk = 2; kk <= 64; kk <<= 1) {
#pragma unroll
      for (int j = kk >> 1; j >= 1; j >>= 1) {
        float ov = shflx_f(sv, j);
        bool keepmax = ((lane & kk) == 0) == ((lane & j) == 0);
        sv = keepmax ? fmaxf(sv, ov) : fminf(sv, ov);
      }
    }
    const float tau = __shfl(sv, 19, 64);
    // count + prefix
    int cnt = 0;
#pragma unroll
    for (int jj = 0; jj < 32; jj++) cnt += (acc[q][jj] >= tau) ? 1 : 0;
    int pre = cnt;
#pragma unroll
    for (int d = 1; d < 64; d <<= 1) {
      int ov = __shfl_up(pre, d, 64);
      if (lane >= d) pre += ov;
    }
    const int kept = __shfl(pre, 63, 64);
    int off = pre - cnt;
    // compact survivors as sortable u64 (score-bits, index) — keys are unique
#pragma unroll
    for (int jj = 0; jj < 32; jj++) {
      float s = acc[q][jj];
      if (s >= tau) {
        unsigned u32 = __float_as_uint(s);
        u32 = (u32 & 0x80000000u) ? ~u32 : (u32 | 0x80000000u);
        buf[off++] = (((ull)u32) << 32) | (unsigned)(jbase + jj);
      }
    }
    asm volatile("s_waitcnt lgkmcnt(0)" ::: "memory");
    int* op = idxout + ((size_t)b * NN + q0 + wave * 4 + q) * KK;
    if (kept <= 64) {
      ull key = (lane < kept) ? buf[lane] : 0ull;
#pragma unroll
      for (int kk = 2; kk <= 64; kk <<= 1) {
#pragma unroll
        for (int j = kk >> 1; j >= 1; j >>= 1) {
          ull ov = shflx_u64(key, j);
          bool keepmax = ((lane & kk) == 0) == ((lane & j) == 0);
          ull mx = key > ov ? key : ov;
          ull mn = key > ov ? ov : key;
          key = keepmax ? mx : mn;
        }
      }
      if (lane < KK) op[lane] = (int)(key & 0xFFFFFFFFu);
    } else {
      // rare fallback: iterative extraction (exact for any kept <= 2048)
      int rounds = (kept + 63) >> 6;
      for (int s = 0; s < KK; s++) {
        ull m = 0; int slot = -1;
        for (int r = 0; r < rounds; r++) {
          int p = lane + (r << 6);
          ull v = (p < kept) ? buf[p] : 0ull;
          if (v > m) { m = v; slot = p; }
        }
        ull gm = m;
#pragma unroll
        for (int d = 1; d < 64; d <<= 1) { ull ov = shflx_u64(gm, d); gm = (ov > gm) ? ov : gm; }
        if (lane == 0) op[s] = (int)(gm & 0xFFFFFFFFu);
        if (m == gm && slot >= 0) buf[slot] = 0ull;
        asm volatile("s_waitcnt lgkmcnt(0)" ::: "memory");
      }
    }
  }
}

// ---------------- U = Wa*x, V = (Wb-Wa)*x ----------------
__global__ __launch_bounds__(256) void uv_kernel(const float* __restrict__ xin,
    const float* __restrict__ w, float* __restrict__ U, float* __restrict__ V,
    int C, int O, long bstride)
{
  const int b = blockIdx.z;
  const int n = blockIdx.x * 64 + (threadIdx.x & 63);
  const int og = __builtin_amdgcn_readfirstlane(threadIdx.x >> 6);  // wave-uniform -> s_loads for w
  const int o0 = blockIdx.y * 32 + og * 8;
  const float* xb = xin + (size_t)b * bstride + n;
  const float* wa = w + (size_t)o0 * 2 * C;
  float au[8], ab[8];
#pragma unroll
  for (int i = 0; i < 8; i++) { au[i] = 0.f; ab[i] = 0.f; }
  for (int c = 0; c < C; c++) {
    float xv = xb[(size_t)c * NN];
#pragma unroll
    for (int i = 0; i < 8; i++) {
      au[i] = fmaf(wa[i * 2 * C + c], xv, au[i]);
      ab[i] = fmaf(wa[i * 2 * C + C + c], xv, ab[i]);
    }
  }
#pragma unroll
  for (int i = 0; i < 8; i++) {
    size_t base = ((size_t)b * O + o0 + i) * NN + n;
    U[base] = au[i];
    V[base] = ab[i] - au[i];
  }
}

// ---------------- edge aggregation: stats + normalized max-over-k ----------------
__global__ __launch_bounds__(256) void edge_kernel(const float* __restrict__ U,
    const float* __restrict__ V, const int* __restrict__ idx,
    float* __restrict__ xo, int O)
{
  __shared__ float Ur[4 * 2052];   // +4 pad breaks the i-stride bank collision
  __shared__ float red[8][4];
  __shared__ float smv[8];
  const int b = blockIdx.y, o0 = blockIdx.x * 4;
  const int t = threadIdx.x, lane = t & 63, wave = t >> 6;
  for (int r = 0; r < 4; r++)
    for (int i = t; i < NN; i += 256)
      Ur[r * 2052 + i] = U[((size_t)b * O + o0 + r) * NN + i];
  __syncthreads();
  const float* Vb = V + ((size_t)b * O + o0) * NN;
  const int* ib = idx + (size_t)b * NN * KK;
  float s0 = 0, s1 = 0, s2 = 0, s3 = 0, c0 = 0, c1 = 0, c2 = 0, c3 = 0;
  for (int n = t; n < NN; n += 256) {
    float v0 = Vb[n], v1 = Vb[NN + n], v2 = Vb[2 * NN + n], v3 = Vb[3 * NN + n];
    const int* ip = ib + (size_t)n * KK;
#pragma unroll
    for (int j = 0; j < KK; j++) {
      int m = ip[j];
      float y0 = Ur[m] + v0, y1 = Ur[2052 + m] + v1;
      float y2 = Ur[4104 + m] + v2, y3 = Ur[6156 + m] + v3;
      s0 += y0; c0 = fmaf(y0, y0, c0);
      s1 += y1; c1 = fmaf(y1, y1, c1);
      s2 += y2; c2 = fmaf(y2, y2, c2);
      s3 += y3; c3 = fmaf(y3, y3, c3);
    }
  }
  float sa[4] = { s0, s1, s2, s3 }, ca[4] = { c0, c1, c2, c3 };
#pragma unroll
  for (int r = 0; r < 4; r++) {
    float a = sa[r], c = ca[r];
#pragma unroll
    for (int d = 1; d < 64; d <<= 1) { a += shflx_f(a, d); c += shflx_f(c, d); }
    if (lane == 0) { red[r][wave] = a; red[4 + r][wave] = c; }
  }
  __syncthreads();
  if (t < 4) {
    float a = red[t][0] + red[t][1] + red[t][2] + red[t][3];
    float c = red[4 + t][0] + red[4 + t][1] + red[4 + t][2] + red[4 + t][3];
    const float inv = 1.f / (float)(NN * KK);
    float mu = a * inv;
    float var = fmaxf(c * inv - mu * mu, 0.f);
    smv[t] = mu;
    smv[4 + t] = rsqrtf(var + EPSF);
  }
  __syncthreads();
  const float mu0 = smv[0], mu1 = smv[1], mu2 = smv[2], mu3 = smv[3];
  const float i0 = smv[4], i1 = smv[5], i2 = smv[6], i3 = smv[7];
  for (int n = t; n < NN; n += 256) {
    float v0 = Vb[n], v1 = Vb[NN + n], v2 = Vb[2 * NN + n], v3 = Vb[3 * NN + n];
    const int* ip = ib + (size_t)n * KK;
    float m0 = -3.4e38f, m1 = m0, m2 = m0, m3 = m0;
#pragma unroll
    for (int j = 0; j < KK; j++) {
      int m = ip[j];
      m0 = fmaxf(m0, Ur[m] + v0);
      m1 = fmaxf(m1, Ur[2052 + m] + v1);
      m2 = fmaxf(m2, Ur[4104 + m] + v2);
      m3 = fmaxf(m3, Ur[6156 + m] + v3);
    }
    float z;  // leaky-relu commutes with max (inv > 0)
    z = (m0 - mu0) * i0; xo[((size_t)b * 512 + o0 + 0) * NN + n] = z >= 0.f ? z : 0.2f * z;
    z = (m1 - mu1) * i1; xo[((size_t)b * 512 + o0 + 1) * NN + n] = z >= 0.f ? z : 0.2f * z;
    z = (m2 - mu2) * i2; xo[((size_t)b * 512 + o0 + 2) * NN + n] = z >= 0.f ? z : 0.2f * z;
    z = (m3 - mu3) * i3; xo[((size_t)b * 512 + o0 + 3) * NN + n] = z >= 0.f ? z : 0.2f * z;
  }
}

// ---------------- final 512x512 GEMM ----------------
__global__ __launch_bounds__(256) void y5_kernel(const float* __restrict__ xcat,
    const float* __restrict__ w5, float* __restrict__ y5)
{
  const int b = blockIdx.z;
  const int n = blockIdx.x * 64 + (threadIdx.x & 63);
  const int og = __builtin_amdgcn_readfirstlane(threadIdx.x >> 6);
  const int o0 = blockIdx.y * 32 + og * 8;
  const float* xb = xcat + (size_t)b * 512 * NN + n;
  const float* wr = w5 + (size_t)o0 * 512;
  float acc[8];
#pragma unroll
  for (int i = 0; i < 8; i++) acc[i] = 0.f;
  for (int c = 0; c < 512; c++) {
    float xv = xb[(size_t)c * NN];
#pragma unroll
    for (int i = 0; i < 8; i++) acc[i] = fmaf(wr[i * 512 + c], xv, acc[i]);
  }
#pragma unroll
  for (int i = 0; i < 8; i++) y5[((size_t)b * 512 + o0 + i) * NN + n] = acc[i];
}

__global__ __launch_bounds__(256) void bn5stat_kernel(const float* __restrict__ y5,
    float* __restrict__ bn5) {
  __shared__ float rs[4], rq[4];
  const int o = blockIdx.x, t = threadIdx.x, lane = t & 63, wave = t >> 6;
  float s = 0.f, q = 0.f;
  for (int b = 0; b < NB; b++) {
    const float* p = y5 + ((size_t)b * 512 + o) * NN;
    for (int n = t; n < NN; n += 256) { float v = p[n]; s += v; q = fmaf(v, v, q); }
  }
#pragma unroll
  for (int d = 1; d < 64; d <<= 1) { s += shflx_f(s, d); q += shflx_f(q, d); }
  if (lane == 0) { rs[wave] = s; rq[wave] = q; }
  __syncthreads();
  if (t == 0) {
    float S = rs[0] + rs[1] + rs[2] + rs[3];
    float Q = rq[0] + rq[1] + rq[2] + rq[3];
    const float inv = 1.f / (float)(NB * NN);
    float mu = S * inv;
    float var = fmaxf(Q * inv - mu * mu, 0.f);
    bn5[o] = mu;
    bn5[512 + o] = rsqrtf(var + EPSF);
  }
}

__global__ __launch_bounds__(256) void final_kernel(const float* __restrict__ y5,
    const float* __restrict__ bn5, const float* __restrict__ gamma,
    const float* __restrict__ beta, float* __restrict__ out)
{
  __shared__ float rm[4], rs[4];
  const int o = blockIdx.x, b = blockIdx.y, t = threadIdx.x, lane = t & 63, wave = t >> 6;
  const float mu = bn5[o], iv = bn5[512 + o], g = gamma[o], be = beta[o];
  const float* p = y5 + ((size_t)b * 512 + o) * NN;
  float mx = -3.4e38f, sm = 0.f;
  for (int n = t; n < NN; n += 256) {
    float z = (p[n] - mu) * iv;
    z = z * g + be;
    z = (z >= 0.f) ? z : 0.2f * z;
    mx = fmaxf(mx, z);
    sm += z;
  }
#pragma unroll
  for (int d = 1; d < 64; d <<= 1) { mx = fmaxf(mx, shflx_f(mx, d)); sm += shflx_f(sm, d); }
  if (lane == 0) { rm[wave] = mx; rs[wave] = sm; }
  __syncthreads();
  if (t == 0) {
    float M = fmaxf(fmaxf(rm[0], rm[1]), fmaxf(rm[2], rm[3]));
    float S = rs[0] + rs[1] + rs[2] + rs[3];
    out[(size_t)b * 1024 + o] = M;
    out[(size_t)b * 1024 + 512 + o] = S * (1.f / NN);
  }
}

extern "C" void kernel_launch(void* const* d_in, const int* in_sizes, int n_in,
                              void* d_out, int out_size, void* d_ws, size_t ws_size,
                              hipStream_t stream)
{
  (void)in_sizes; (void)n_in; (void)out_size; (void)ws_size;
  const float* x  = (const float*)d_in[0];
  const float* w1 = (const float*)d_in[1];
  const float* w2 = (const float*)d_in[2];
  const float* w3 = (const float*)d_in[3];
  const float* w4 = (const float*)d_in[4];
  const float* w5 = (const float*)d_in[5];
  const float* g5 = (const float*)d_in[6];
  const float* b5 = (const float*)d_in[7];
  float* out = (float*)d_out;

  // workspace layout (~137 MB)
  float* ws   = (float*)d_ws;
  float* xcat = ws;                         // 16*512*2048
  float* Ub   = xcat + 16777216;            // 16*256*2048
  float* Vb   = Ub + 8388608;               // 16*256*2048
  int*   idxb = (int*)(Vb + 8388608);       // 16*2048*20
  float* xxb  = (float*)(idxb + 655360);    // 16*2048
  float* bn5  = xxb + 32768;                // 1024
  float* y5   = Ub;                         // reuse U/V space after layer 4

  struct Lyr { const float* xin; long bstride; int C, O, coff; const float* w; };
  const Lyr L[4] = {
    { x,              3L * NN,   3,   64,  0,   w1 },
    { xcat,           512L * NN, 64,  64,  64,  w2 },
    { xcat + 64 * NN, 512L * NN, 64,  128, 128, w3 },
    { xcat + 128 * NN,512L * NN, 128, 256, 256, w4 },
  };

  for (int l = 0; l < 4; l++) {
    xx_kernel<<<dim3(NN / 256, NB), 256, 0, stream>>>(L[l].xin, xxb, L[l].C, L[l].bstride);
    knn_kernel<<<dim3(NN / 16, NB), 256, 0, stream>>>(L[l].xin, xxb, idxb, L[l].C, L[l].bstride);
    uv_kernel<<<dim3(NN / 64, L[l].O / 32, NB), 256, 0, stream>>>(L[l].xin, L[l].w, Ub, Vb,
                                                                  L[l].C, L[l].O, L[l].bstride);
    edge_kernel<<<dim3(L[l].O / 4, NB), 256, 0, stream>>>(Ub, Vb, idxb,
                                                          xcat + (size_t)L[l].coff * NN, L[l].O);
  }
  y5_kernel<<<dim3(NN / 64, 16, NB), 256, 0, stream>>>(xcat, w5, y5);
  bn5stat_kernel<<<512, 256, 0, stream>>>(y5, bn5);
  final_kernel<<<dim3(512, NB), 256, 0, stream>>>(y5, bn5, g5, b5, out);
}

// Round 2
// 3026.852 us; speedup vs baseline: 1.2673x; 1.2673x over previous
//
#include <hip/hip_runtime.h>

#define NN 2048      // points
#define NB 16        // batch
#define KK 20        // k neighbors
#define EPSF 1e-5f

typedef unsigned long long ull;

__device__ __forceinline__ float shflx_f(float v, int m) { return __shfl_xor(v, m, 64); }
__device__ __forceinline__ ull shflx_u64(ull v, int m) {
  int lo = __shfl_xor((int)(unsigned)v, m, 64);
  int hi = __shfl_xor((int)(unsigned)(v >> 32), m, 64);
  return (((ull)(unsigned)hi) << 32) | (unsigned)lo;
}

// ---------------- squared norms ----------------
__global__ __launch_bounds__(256) void xx_kernel(const float* __restrict__ x,
    float* __restrict__ xx, int C, long bstride) {
  const int b = blockIdx.y;
  const int n = blockIdx.x * 256 + threadIdx.x;
  const float* xb = x + (size_t)b * bstride;
  float s = 0.f;
  for (int c = 0; c < C; c++) { float v = xb[(size_t)c * NN + n]; s = fmaf(v, v, s); }
  xx[b * NN + n] = s;
}

// ---------------- kNN v2: 16 queries/block, candidates in two 1024-halves ----
// score(i,j) = dot(x_i,x_j) - 0.5*||x_j||^2  (same ordering as reference pd)
// acc[4][16] stays in VGPRs (no AGPR thrash); LDS 40KB -> 4 blocks/CU.
__global__ __launch_bounds__(256) void knn_kernel(const float* __restrict__ xin,
    const float* __restrict__ xxg, int* __restrict__ idxout, int C, long bstride)
{
  __shared__ __align__(16) float xr[4 * 1024];   // 16KB: 4 c-rows x 1024 candidates
  __shared__ float xq[16 * 128];                 // 8KB: 16 query vectors
  __shared__ ull swb[4][4][128];                 // 16KB: survivors per (wave, q)
  const int t = threadIdx.x;
  const int lane = t & 63;
  const int wave = t >> 6;
  const int b = blockIdx.y;
  const int q0 = blockIdx.x * 16;
  const float* xb = xin + (size_t)b * bstride;

  for (int i = t; i < 16 * C; i += 256) {
    int q = i / C, c = i - q * C;
    xq[q * 128 + c] = xb[(size_t)c * NN + q0 + q];
  }

  int off[4] = { 0, 0, 0, 0 };
  float4 pf[4];
  {  // prefetch first chunk (h=0, cc=0)
    const int nr = C < 4 ? C : 4;
    for (int r = 0; r < nr; r++)
      pf[r] = ((const float4*)(xb + (size_t)r * NN))[t];
  }

  for (int h = 0; h < 2; h++) {
    float acc[4][16];
#pragma unroll
    for (int q = 0; q < 4; q++)
#pragma unroll
      for (int jj = 0; jj < 16; jj++) acc[q][jj] = 0.f;

    auto comp = [&](int r) {
      const float qv0 = xq[(wave * 4 + 0) * 128 + 0];  // placeholder, replaced below
      (void)qv0;
    };
    (void)comp;

    for (int cc = 0; cc < C; cc += 4) {
      const int nr = (C - cc) < 4 ? (C - cc) : 4;
      __syncthreads();
      for (int r = 0; r < nr; r++)
        ((float4*)&xr[r * 1024])[t] = pf[r];
      __syncthreads();
      // prefetch next chunk (next cc, or first chunk of half 1)
      {
        int nh = h, ncc = cc + 4;
        if (ncc >= C) { nh++; ncc = 0; }
        if (nh < 2) {
          const float* base = xb + (size_t)ncc * NN + nh * 1024;
          const int nr2 = (C - ncc) < 4 ? (C - ncc) : 4;
          for (int r = 0; r < nr2; r++)
            pf[r] = ((const float4*)(base + (size_t)r * NN))[t];
        }
      }
      // compute: 4 queries x 16 candidates per lane, candidates {2*lane + 128*u}
#define COMP_R(r) {                                                          \
        const float qv0 = xq[(wave * 4 + 0) * 128 + cc + (r)];               \
        const float qv1 = xq[(wave * 4 + 1) * 128 + cc + (r)];               \
        const float qv2 = xq[(wave * 4 + 2) * 128 + cc + (r)];               \
        const float qv3 = xq[(wave * 4 + 3) * 128 + cc + (r)];               \
        _Pragma("unroll")                                                    \
        for (int u = 0; u < 8; u++) {                                        \
          const float2 xv = *(const float2*)&xr[(r) * 1024 + 2 * lane + 128 * u]; \
          acc[0][2*u]   = fmaf(qv0, xv.x, acc[0][2*u]);                      \
          acc[0][2*u+1] = fmaf(qv0, xv.y, acc[0][2*u+1]);                    \
          acc[1][2*u]   = fmaf(qv1, xv.x, acc[1][2*u]);                      \
          acc[1][2*u+1] = fmaf(qv1, xv.y, acc[1][2*u+1]);                    \
          acc[2][2*u]   = fmaf(qv2, xv.x, acc[2][2*u]);                      \
          acc[2][2*u+1] = fmaf(qv2, xv.y, acc[2][2*u+1]);                    \
          acc[3][2*u]   = fmaf(qv3, xv.x, acc[3][2*u]);                      \
          acc[3][2*u+1] = fmaf(qv3, xv.y, acc[3][2*u+1]);                    \
        }                                                                    \
      }
      if (nr == 4) {
        COMP_R(0) COMP_R(1) COMP_R(2) COMP_R(3)
      } else {
        for (int r = 0; r < nr; r++) COMP_R(r)
      }
#undef COMP_R
    }

    // scores = acc - 0.5*xx[j]
    {
      const float* xxb = xxg + b * NN + h * 1024;
#pragma unroll
      for (int u = 0; u < 8; u++) {
        const float2 xv = *(const float2*)&xxb[2 * lane + 128 * u];
#pragma unroll
        for (int q = 0; q < 4; q++) {
          acc[q][2*u]   -= 0.5f * xv.x;
          acc[q][2*u+1] -= 0.5f * xv.y;
        }
      }
    }

    // per-half tau filter + compact survivors (persistent across halves)
#pragma unroll
    for (int q = 0; q < 4; q++) {
      float lm = acc[q][0];
#pragma unroll
      for (int jj = 1; jj < 16; jj++) lm = fmaxf(lm, acc[q][jj]);
      // bitonic sort of 64 lane-maxima (descending); tau = rank-19 value.
      // At most 19 candidates exceed this half's 20th-largest, so tau <= t20(half):
      // filter "v >= tau" keeps all of this half's top-20 (superset of its members
      // of the global top-20).
      float sv = lm;
#pragma unroll
      for (int kk = 2; kk <= 64; kk <<= 1) {
#pragma unroll
        for (int j = kk >> 1; j >= 1; j >>= 1) {
          float ov = shflx_f(sv, j);
          bool keepmax = ((lane & kk) == 0) == ((lane & j) == 0);
          sv = keepmax ? fmaxf(sv, ov) : fminf(sv, ov);
        }
      }
      const float tau = __shfl(sv, 19, 64);
      int cnt = 0;
#pragma unroll
      for (int jj = 0; jj < 16; jj++) cnt += (acc[q][jj] >= tau) ? 1 : 0;
      int pre = cnt;
#pragma unroll
      for (int d = 1; d < 64; d <<= 1) {
        int ov = __shfl_up(pre, d, 64);
        if (lane >= d) pre += ov;
      }
      const int keph = __shfl(pre, 63, 64);
      int p = off[q] + pre - cnt;
#pragma unroll
      for (int jj = 0; jj < 16; jj++) {
        float s = acc[q][jj];
        if (s >= tau) {
          unsigned u32 = __float_as_uint(s);
          u32 = (u32 & 0x80000000u) ? ~u32 : (u32 | 0x80000000u);
          int j = h * 1024 + 2 * lane + 128 * (jj >> 1) + (jj & 1);
          if (p < 128) swb[wave][q][p] = (((ull)u32) << 32) | (unsigned)j;
          p++;
        }
      }
      off[q] += keph;
    }
  }

  asm volatile("s_waitcnt lgkmcnt(0)" ::: "memory");

  // final selection per query: sort combined survivors (typical ~48)
#pragma unroll
  for (int q = 0; q < 4; q++) {
    const int total = off[q] < 128 ? off[q] : 128;
    int* op = idxout + ((size_t)b * NN + q0 + wave * 4 + q) * KK;
    if (total <= 64) {
      ull key = (lane < total) ? swb[wave][q][lane] : 0ull;
#pragma unroll
      for (int kk = 2; kk <= 64; kk <<= 1) {
#pragma unroll
        for (int j = kk >> 1; j >= 1; j >>= 1) {
          ull ov = shflx_u64(key, j);
          bool keepmax = ((lane & kk) == 0) == ((lane & j) == 0);
          ull mx = key > ov ? key : ov;
          ull mn = key > ov ? ov : key;
          key = keepmax ? mx : mn;
        }
      }
      if (lane < KK) op[lane] = (int)(key & 0xFFFFFFFFu);
    } else {
      // rare fallback: iterative extraction (exact for any total <= 128)
      const int rounds = (total + 63) >> 6;
      for (int s = 0; s < KK; s++) {
        ull m = 0; int slot = -1;
        for (int r = 0; r < rounds; r++) {
          int p = lane + (r << 6);
          ull v = (p < total) ? swb[wave][q][p] : 0ull;
          if (v > m) { m = v; slot = p; }
        }
        ull gm = m;
#pragma unroll
        for (int d = 1; d < 64; d <<= 1) { ull ov = shflx_u64(gm, d); gm = (ov > gm) ? ov : gm; }
        if (lane == 0) op[s] = (int)(gm & 0xFFFFFFFFu);
        if (m == gm && slot >= 0) swb[wave][q][slot] = 0ull;
        asm volatile("s_waitcnt lgkmcnt(0)" ::: "memory");
      }
    }
  }
}

// ---------------- U = Wa*x, V = (Wb-Wa)*x ----------------
__global__ __launch_bounds__(256) void uv_kernel(const float* __restrict__ xin,
    const float* __restrict__ w, float* __restrict__ U, float* __restrict__ V,
    int C, int O, long bstride)
{
  const int b = blockIdx.z;
  const int n = blockIdx.x * 64 + (threadIdx.x & 63);
  const int og = __builtin_amdgcn_readfirstlane(threadIdx.x >> 6);  // wave-uniform -> s_loads for w
  const int o0 = blockIdx.y * 32 + og * 8;
  const float* xb = xin + (size_t)b * bstride + n;
  const float* wa = w + (size_t)o0 * 2 * C;
  float au[8], ab[8];
#pragma unroll
  for (int i = 0; i < 8; i++) { au[i] = 0.f; ab[i] = 0.f; }
  for (int c = 0; c < C; c++) {
    float xv = xb[(size_t)c * NN];
#pragma unroll
    for (int i = 0; i < 8; i++) {
      au[i] = fmaf(wa[i * 2 * C + c], xv, au[i]);
      ab[i] = fmaf(wa[i * 2 * C + C + c], xv, ab[i]);
    }
  }
#pragma unroll
  for (int i = 0; i < 8; i++) {
    size_t base = ((size_t)b * O + o0 + i) * NN + n;
    U[base] = au[i];
    V[base] = ab[i] - au[i];
  }
}

// ---------------- edge aggregation: stats + normalized max-over-k ----------------
__global__ __launch_bounds__(256) void edge_kernel(const float* __restrict__ U,
    const float* __restrict__ V, const int* __restrict__ idx,
    float* __restrict__ xo, int O)
{
  __shared__ float Ur[4 * 2052];   // +4 pad breaks the i-stride bank collision
  __shared__ float red[8][4];
  __shared__ float smv[8];
  const int b = blockIdx.y, o0 = blockIdx.x * 4;
  const int t = threadIdx.x, lane = t & 63, wave = t >> 6;
  for (int r = 0; r < 4; r++)
    for (int i = t; i < NN; i += 256)
      Ur[r * 2052 + i] = U[((size_t)b * O + o0 + r) * NN + i];
  __syncthreads();
  const float* Vb = V + ((size_t)b * O + o0) * NN;
  const int* ib = idx + (size_t)b * NN * KK;
  float s0 = 0, s1 = 0, s2 = 0, s3 = 0, c0 = 0, c1 = 0, c2 = 0, c3 = 0;
  for (int n = t; n < NN; n += 256) {
    float v0 = Vb[n], v1 = Vb[NN + n], v2 = Vb[2 * NN + n], v3 = Vb[3 * NN + n];
    const int* ip = ib + (size_t)n * KK;
#pragma unroll
    for (int j = 0; j < KK; j++) {
      int m = ip[j];
      float y0 = Ur[m] + v0, y1 = Ur[2052 + m] + v1;
      float y2 = Ur[4104 + m] + v2, y3 = Ur[6156 + m] + v3;
      s0 += y0; c0 = fmaf(y0, y0, c0);
      s1 += y1; c1 = fmaf(y1, y1, c1);
      s2 += y2; c2 = fmaf(y2, y2, c2);
      s3 += y3; c3 = fmaf(y3, y3, c3);
    }
  }
  float sa[4] = { s0, s1, s2, s3 }, ca[4] = { c0, c1, c2, c3 };
#pragma unroll
  for (int r = 0; r < 4; r++) {
    float a = sa[r], c = ca[r];
#pragma unroll
    for (int d = 1; d < 64; d <<= 1) { a += shflx_f(a, d); c += shflx_f(c, d); }
    if (lane == 0) { red[r][wave] = a; red[4 + r][wave] = c; }
  }
  __syncthreads();
  if (t < 4) {
    float a = red[t][0] + red[t][1] + red[t][2] + red[t][3];
    float c = red[4 + t][0] + red[4 + t][1] + red[4 + t][2] + red[4 + t][3];
    const float inv = 1.f / (float)(NN * KK);
    float mu = a * inv;
    float var = fmaxf(c * inv - mu * mu, 0.f);
    smv[t] = mu;
    smv[4 + t] = rsqrtf(var + EPSF);
  }
  __syncthreads();
  const float mu0 = smv[0], mu1 = smv[1], mu2 = smv[2], mu3 = smv[3];
  const float i0 = smv[4], i1 = smv[5], i2 = smv[6], i3 = smv[7];
  for (int n = t; n < NN; n += 256) {
    float v0 = Vb[n], v1 = Vb[NN + n], v2 = Vb[2 * NN + n], v3 = Vb[3 * NN + n];
    const int* ip = ib + (size_t)n * KK;
    float m0 = -3.4e38f, m1 = m0, m2 = m0, m3 = m0;
#pragma unroll
    for (int j = 0; j < KK; j++) {
      int m = ip[j];
      m0 = fmaxf(m0, Ur[m] + v0);
      m1 = fmaxf(m1, Ur[2052 + m] + v1);
      m2 = fmaxf(m2, Ur[4104 + m] + v2);
      m3 = fmaxf(m3, Ur[6156 + m] + v3);
    }
    float z;  // leaky-relu commutes with max (inv > 0)
    z = (m0 - mu0) * i0; xo[((size_t)b * 512 + o0 + 0) * NN + n] = z >= 0.f ? z : 0.2f * z;
    z = (m1 - mu1) * i1; xo[((size_t)b * 512 + o0 + 1) * NN + n] = z >= 0.f ? z : 0.2f * z;
    z = (m2 - mu2) * i2; xo[((size_t)b * 512 + o0 + 2) * NN + n] = z >= 0.f ? z : 0.2f * z;
    z = (m3 - mu3) * i3; xo[((size_t)b * 512 + o0 + 3) * NN + n] = z >= 0.f ? z : 0.2f * z;
  }
}

// ---------------- final 512x512 GEMM ----------------
__global__ __launch_bounds__(256) void y5_kernel(const float* __restrict__ xcat,
    const float* __restrict__ w5, float* __restrict__ y5)
{
  const int b = blockIdx.z;
  const int n = blockIdx.x * 64 + (threadIdx.x & 63);
  const int og = __builtin_amdgcn_readfirstlane(threadIdx.x >> 6);
  const int o0 = blockIdx.y * 32 + og * 8;
  const float* xb = xcat + (size_t)b * 512 * NN + n;
  const float* wr = w5 + (size_t)o0 * 512;
  float acc[8];
#pragma unroll
  for (int i = 0; i < 8; i++) acc[i] = 0.f;
  for (int c = 0; c < 512; c++) {
    float xv = xb[(size_t)c * NN];
#pragma unroll
    for (int i = 0; i < 8; i++) acc[i] = fmaf(wr[i * 512 + c], xv, acc[i]);
  }
#pragma unroll
  for (int i = 0; i < 8; i++) y5[((size_t)b * 512 + o0 + i) * NN + n] = acc[i];
}

__global__ __launch_bounds__(256) void bn5stat_kernel(const float* __restrict__ y5,
    float* __restrict__ bn5) {
  __shared__ float rs[4], rq[4];
  const int o = blockIdx.x, t = threadIdx.x, lane = t & 63, wave = t >> 6;
  float s = 0.f, q = 0.f;
  for (int b = 0; b < NB; b++) {
    const float* p = y5 + ((size_t)b * 512 + o) * NN;
    for (int n = t; n < NN; n += 256) { float v = p[n]; s += v; q = fmaf(v, v, q); }
  }
#pragma unroll
  for (int d = 1; d < 64; d <<= 1) { s += shflx_f(s, d); q += shflx_f(q, d); }
  if (lane == 0) { rs[wave] = s; rq[wave] = q; }
  __syncthreads();
  if (t == 0) {
    float S = rs[0] + rs[1] + rs[2] + rs[3];
    float Q = rq[0] + rq[1] + rq[2] + rq[3];
    const float inv = 1.f / (float)(NB * NN);
    float mu = S * inv;
    float var = fmaxf(Q * inv - mu * mu, 0.f);
    bn5[o] = mu;
    bn5[512 + o] = rsqrtf(var + EPSF);
  }
}

__global__ __launch_bounds__(256) void final_kernel(const float* __restrict__ y5,
    const float* __restrict__ bn5, const float* __restrict__ gamma,
    const float* __restrict__ beta, float* __restrict__ out)
{
  __shared__ float rm[4], rs[4];
  const int o = blockIdx.x, b = blockIdx.y, t = threadIdx.x, lane = t & 63, wave = t >> 6;
  const float mu = bn5[o], iv = bn5[512 + o], g = gamma[o], be = beta[o];
  const float* p = y5 + ((size_t)b * 512 + o) * NN;
  float mx = -3.4e38f, sm = 0.f;
  for (int n = t; n < NN; n += 256) {
    float z = (p[n] - mu) * iv;
    z = z * g + be;
    z = (z >= 0.f) ? z : 0.2f * z;
    mx = fmaxf(mx, z);
    sm += z;
  }
#pragma unroll
  for (int d = 1; d < 64; d <<= 1) { mx = fmaxf(mx, shflx_f(mx, d)); sm += shflx_f(sm, d); }
  if (lane == 0) { rm[wave] = mx; rs[wave] = sm; }
  __syncthreads();
  if (t == 0) {
    float M = fmaxf(fmaxf(rm[0], rm[1]), fmaxf(rm[2], rm[3]));
    float S = rs[0] + rs[1] + rs[2] + rs[3];
    out[(size_t)b * 1024 + o] = M;
    out[(size_t)b * 1024 + 512 + o] = S * (1.f / NN);
  }
}

extern "C" void kernel_launch(void* const* d_in, const int* in_sizes, int n_in,
                              void* d_out, int out_size, void* d_ws, size_t ws_size,
                              hipStream_t stream)
{
  (void)in_sizes; (void)n_in; (void)out_size; (void)ws_size;
  const float* x  = (const float*)d_in[0];
  const float* w1 = (const float*)d_in[1];
  const float* w2 = (const float*)d_in[2];
  const float* w3 = (const float*)d_in[3];
  const float* w4 = (const float*)d_in[4];
  const float* w5 = (const float*)d_in[5];
  const float* g5 = (const float*)d_in[6];
  const float* b5 = (const float*)d_in[7];
  float* out = (float*)d_out;

  // workspace layout (~137 MB)
  float* ws   = (float*)d_ws;
  float* xcat = ws;                         // 16*512*2048
  float* Ub   = xcat + 16777216;            // 16*256*2048
  float* Vb   = Ub + 8388608;               // 16*256*2048
  int*   idxb = (int*)(Vb + 8388608);       // 16*2048*20
  float* xxb  = (float*)(idxb + 655360);    // 16*2048
  float* bn5  = xxb + 32768;                // 1024
  float* y5   = Ub;                         // reuse U/V space after layer 4

  struct Lyr { const float* xin; long bstride; int C, O, coff; const float* w; };
  const Lyr L[4] = {
    { x,              3L * NN,   3,   64,  0,   w1 },
    { xcat,           512L * NN, 64,  64,  64,  w2 },
    { xcat + 64 * NN, 512L * NN, 64,  128, 128, w3 },
    { xcat + 128 * NN,512L * NN, 128, 256, 256, w4 },
  };

  for (int l = 0; l < 4; l++) {
    xx_kernel<<<dim3(NN / 256, NB), 256, 0, stream>>>(L[l].xin, xxb, L[l].C, L[l].bstride);
    knn_kernel<<<dim3(NN / 16, NB), 256, 0, stream>>>(L[l].xin, xxb, idxb, L[l].C, L[l].bstride);
    uv_kernel<<<dim3(NN / 64, L[l].O / 32, NB), 256, 0, stream>>>(L[l].xin, L[l].w, Ub, Vb,
                                                                  L[l].C, L[l].O, L[l].bstride);
    edge_kernel<<<dim3(L[l].O / 4, NB), 256, 0, stream>>>(Ub, Vb, idxb,
                                                          xcat + (size_t)L[l].coff * NN, L[l].O);
  }
  y5_kernel<<<dim3(NN / 64, 16, NB), 256, 0, stream>>>(xcat, w5, y5);
  bn5stat_kernel<<<512, 256, 0, stream>>>(y5, bn5);
  final_kernel<<<dim3(512, NB), 256, 0, stream>>>(y5, bn5, g5, b5, out);
}

// Round 3
// 2308.951 us; speedup vs baseline: 1.6613x; 1.3109x over previous
//
#include <hip/hip_runtime.h>

#define NN 2048      // points
#define NB 16        // batch
#define KK 20        // k neighbors
#define EPSF 1e-5f

typedef unsigned long long ull;
typedef _Float16 v8h __attribute__((ext_vector_type(8)));
typedef float v4f __attribute__((ext_vector_type(4)));

__device__ __forceinline__ float shflx_f(float v, int m) { return __shfl_xor(v, m, 64); }
__device__ __forceinline__ ull shflx_u64(ull v, int m) {
  int lo = __shfl_xor((int)(unsigned)v, m, 64);
  int hi = __shfl_xor((int)(unsigned)(v >> 32), m, 64);
  return (((ull)(unsigned)hi) << 32) | (unsigned)lo;
}

// ---------------- prep: x[C][N] fp32 -> fragment-ready f16 hi/lo [n][Cp] + xx ----
__global__ __launch_bounds__(256) void prep_kernel(const float* __restrict__ x,
    _Float16* __restrict__ xh, _Float16* __restrict__ xl, float* __restrict__ xx,
    int C, int KB, long bstride)
{
  const int b = blockIdx.y;
  const int n = blockIdx.x * 256 + threadIdx.x;
  const float* xb = x + (size_t)b * bstride;
  const int Cp = KB * 32;
  _Float16* ph = xh + ((size_t)b * NN + n) * Cp;
  _Float16* pl = xl + ((size_t)b * NN + n) * Cp;
  float s = 0.f;
  for (int kb = 0; kb < KB; kb++) {
    for (int g = 0; g < 4; g++) {
      v8h hv, lv;
#pragma unroll
      for (int j = 0; j < 8; j++) {
        int c = kb * 32 + g * 8 + j;
        float v = (c < C) ? xb[(size_t)c * NN + n] : 0.f;
        _Float16 h = (_Float16)v;
        hv[j] = h;
        lv[j] = (_Float16)(v - (float)h);
        s = fmaf(v, v, s);
      }
      *(v8h*)(ph + kb * 32 + g * 8) = hv;
      *(v8h*)(pl + kb * 32 + g * 8) = lv;
    }
  }
  xx[b * NN + n] = s;
}

// ---------------- MFMA tile scorer: 16 queries x 16 candidates, exact fp16x4 ----
template<int KB>
__device__ __forceinline__ v4f score_tile(const _Float16* __restrict__ xhb,
    const _Float16* __restrict__ xlb, const v8h* Ah, const v8h* Al,
    int nbase, int quad8)
{
  const int Cp = KB * 32;
  v4f a0 = {0.f, 0.f, 0.f, 0.f};
  v4f a1 = {0.f, 0.f, 0.f, 0.f};
  const _Float16* ph = xhb + (size_t)nbase * Cp + quad8;
  const _Float16* pl = xlb + (size_t)nbase * Cp + quad8;
#pragma unroll
  for (int kb = 0; kb < KB; kb++) {
    v8h bh = *(const v8h*)(ph + kb * 32);
    v8h bl = *(const v8h*)(pl + kb * 32);
    a0 = __builtin_amdgcn_mfma_f32_16x16x32_f16(Ah[kb], bh, a0, 0, 0, 0);
    a1 = __builtin_amdgcn_mfma_f32_16x16x32_f16(Al[kb], bh, a1, 0, 0, 0);
    a0 = __builtin_amdgcn_mfma_f32_16x16x32_f16(Ah[kb], bl, a0, 0, 0, 0);
    a1 = __builtin_amdgcn_mfma_f32_16x16x32_f16(Al[kb], bl, a1, 0, 0, 0);
  }
  return a0 + a1;
}

// ---------------- kNN via MFMA: 64 queries/block (16/wave), exact top-20 -------
// score(i,j) = dot(x_i,x_j) - 0.5*||x_j||^2; D-layout: col(lane&15)=candidate,
// row(quad*4+reg)=query. Pass 1: 32 group-maxima/query -> tau = rank-19 (<= t20).
// Pass 2: bitwise-identical rescore, compact survivors >= tau, sort top-20.
// Barrier-free: all LDS state is wave-private.
template<int KB>
__global__ __launch_bounds__(256) void knn_mfma(
    const _Float16* __restrict__ xh, const _Float16* __restrict__ xl,
    const float* __restrict__ xxg, int* __restrict__ idxout)
{
  __shared__ float gmL[64][33];
  __shared__ float tauL[64];
  __shared__ int scnt[64];
  __shared__ ull slist[64][128];

  const int t = threadIdx.x;
  const int lane = t & 63;
  const int wave = t >> 6;
  const int col = lane & 15;
  const int quad = lane >> 4;
  const int quad8 = quad * 8;
  const int b = blockIdx.y;
  const int q0 = blockIdx.x * 64;
  const int Cp = KB * 32;
  const _Float16* xhb = xh + (size_t)b * NN * Cp;
  const _Float16* xlb = xl + (size_t)b * NN * Cp;
  const float* xxb = xxg + b * NN;

  // A fragments (16 queries of this wave), held for the whole kernel
  v8h Ah[KB], Al[KB];
  {
    const _Float16* pa = xhb + (size_t)(q0 + wave * 16 + col) * Cp + quad8;
    const _Float16* pb = xlb + (size_t)(q0 + wave * 16 + col) * Cp + quad8;
#pragma unroll
    for (int kb = 0; kb < KB; kb++) {
      Ah[kb] = *(const v8h*)(pa + kb * 32);
      Al[kb] = *(const v8h*)(pb + kb * 32);
    }
  }

  // ---- pass 1: per-(col,parity) running maxima over 128 candidate tiles ----
  float gm0[4] = { -3.4e38f, -3.4e38f, -3.4e38f, -3.4e38f };
  float gm1[4] = { -3.4e38f, -3.4e38f, -3.4e38f, -3.4e38f };
  for (int tt = 0; tt < 128; tt += 2) {
    int n0 = tt * 16 + col, n1 = n0 + 16;
    float xv0 = xxb[n0], xv1 = xxb[n1];
    v4f s0 = score_tile<KB>(xhb, xlb, Ah, Al, n0, quad8);
    v4f s1 = score_tile<KB>(xhb, xlb, Ah, Al, n1, quad8);
#pragma unroll
    for (int j = 0; j < 4; j++) {
      gm0[j] = fmaxf(gm0[j], s0[j] - 0.5f * xv0);
      gm1[j] = fmaxf(gm1[j], s1[j] - 0.5f * xv1);
    }
  }
#pragma unroll
  for (int j = 0; j < 4; j++) {
    gmL[wave * 16 + quad * 4 + j][col * 2] = gm0[j];
    gmL[wave * 16 + quad * 4 + j][col * 2 + 1] = gm1[j];
  }
  asm volatile("s_waitcnt lgkmcnt(0)" ::: "memory");

  // ---- tau: rank-19 of each query's 32 group maxima (two queries per round) --
  for (int r = 0; r < 8; r++) {
    const int q = wave * 16 + r * 2 + (lane >> 5);
    const int idx = lane & 31;
    float v = gmL[q][idx];
#pragma unroll
    for (int kk = 2; kk <= 32; kk <<= 1) {
#pragma unroll
      for (int m = kk >> 1; m >= 1; m >>= 1) {
        float o = shflx_f(v, m);
        bool keepmax = ((idx & kk) == 0) == ((idx & m) == 0);
        v = keepmax ? fmaxf(v, o) : fminf(v, o);
      }
    }
    if (idx == 19) tauL[q] = v;
  }
  if (lane < 16) scnt[wave * 16 + lane] = 0;
  asm volatile("s_waitcnt lgkmcnt(0)" ::: "memory");

  float tq[4];
#pragma unroll
  for (int j = 0; j < 4; j++) tq[j] = tauL[wave * 16 + quad * 4 + j];

  // ---- pass 2: bitwise-identical rescore, compact survivors ----
  for (int tt = 0; tt < 128; tt += 2) {
    int n0 = tt * 16 + col, n1 = n0 + 16;
    float xv0 = xxb[n0], xv1 = xxb[n1];
    v4f s0 = score_tile<KB>(xhb, xlb, Ah, Al, n0, quad8);
    v4f s1 = score_tile<KB>(xhb, xlb, Ah, Al, n1, quad8);
#pragma unroll
    for (int j = 0; j < 4; j++) {
      float sa = s0[j] - 0.5f * xv0;
      float sb = s1[j] - 0.5f * xv1;
      int q = wave * 16 + quad * 4 + j;
      if (sa >= tq[j]) {
        int pos = atomicAdd(&scnt[q], 1);
        if (pos < 128) {
          unsigned u = __float_as_uint(sa);
          u = (u & 0x80000000u) ? ~u : (u | 0x80000000u);
          slist[q][pos] = (((ull)u) << 32) | (unsigned)(2047 - n0);
        }
      }
      if (sb >= tq[j]) {
        int pos = atomicAdd(&scnt[q], 1);
        if (pos < 128) {
          unsigned u = __float_as_uint(sb);
          u = (u & 0x80000000u) ? ~u : (u | 0x80000000u);
          slist[q][pos] = (((ull)u) << 32) | (unsigned)(2047 - n1);
        }
      }
    }
  }
  asm volatile("s_waitcnt lgkmcnt(0)" ::: "memory");

  // ---- final top-20 per query (ties -> lowest index, matching stable top_k) --
  for (int qi = 0; qi < 16; qi++) {
    const int q = wave * 16 + qi;
    int total = scnt[q];
    if (total > 128) total = 128;
    int* op = idxout + ((size_t)b * NN + q0 + wave * 16 + qi) * KK;
    if (total <= 64) {
      ull key = (lane < total) ? slist[q][lane] : 0ull;
#pragma unroll
      for (int kk = 2; kk <= 64; kk <<= 1) {
#pragma unroll
        for (int j = kk >> 1; j >= 1; j >>= 1) {
          ull ov = shflx_u64(key, j);
          bool keepmax = ((lane & kk) == 0) == ((lane & j) == 0);
          ull mx = key > ov ? key : ov;
          ull mn = key > ov ? ov : key;
          key = keepmax ? mx : mn;
        }
      }
      if (lane < KK) op[lane] = 2047 - (int)(key & 0xFFFFFFFFu);
    } else {
      const int rounds = (total + 63) >> 6;
      for (int s = 0; s < KK; s++) {
        ull m = 0; int slot = -1;
        for (int r = 0; r < rounds; r++) {
          int p = lane + (r << 6);
          ull v = (p < total) ? slist[q][p] : 0ull;
          if (v > m) { m = v; slot = p; }
        }
        ull gmx = m;
#pragma unroll
        for (int d = 1; d < 64; d <<= 1) { ull ov = shflx_u64(gmx, d); gmx = (ov > gmx) ? ov : gmx; }
        if (lane == 0) op[s] = 2047 - (int)(gmx & 0xFFFFFFFFu);
        if (m == gmx && slot >= 0) slist[q][slot] = 0ull;
        asm volatile("s_waitcnt lgkmcnt(0)" ::: "memory");
      }
    }
  }
}

// ---------------- U = Wa*x, V = (Wb-Wa)*x ----------------
__global__ __launch_bounds__(256) void uv_kernel(const float* __restrict__ xin,
    const float* __restrict__ w, float* __restrict__ U, float* __restrict__ V,
    int C, int O, long bstride)
{
  const int b = blockIdx.z;
  const int n = blockIdx.x * 64 + (threadIdx.x & 63);
  const int og = __builtin_amdgcn_readfirstlane(threadIdx.x >> 6);  // wave-uniform -> s_loads for w
  const int o0 = blockIdx.y * 32 + og * 8;
  const float* xb = xin + (size_t)b * bstride + n;
  const float* wa = w + (size_t)o0 * 2 * C;
  float au[8], ab[8];
#pragma unroll
  for (int i = 0; i < 8; i++) { au[i] = 0.f; ab[i] = 0.f; }
  for (int c = 0; c < C; c++) {
    float xv = xb[(size_t)c * NN];
#pragma unroll
    for (int i = 0; i < 8; i++) {
      au[i] = fmaf(wa[i * 2 * C + c], xv, au[i]);
      ab[i] = fmaf(wa[i * 2 * C + C + c], xv, ab[i]);
    }
  }
#pragma unroll
  for (int i = 0; i < 8; i++) {
    size_t base = ((size_t)b * O + o0 + i) * NN + n;
    U[base] = au[i];
    V[base] = ab[i] - au[i];
  }
}

// ---------------- edge aggregation: stats + normalized max-over-k ----------------
__global__ __launch_bounds__(256) void edge_kernel(const float* __restrict__ U,
    const float* __restrict__ V, const int* __restrict__ idx,
    float* __restrict__ xo, int O)
{
  __shared__ float Ur[4 * 2052];   // +4 pad breaks the i-stride bank collision
  __shared__ float red[8][4];
  __shared__ float smv[8];
  const int b = blockIdx.y, o0 = blockIdx.x * 4;
  const int t = threadIdx.x, lane = t & 63, wave = t >> 6;
  for (int r = 0; r < 4; r++)
    for (int i = t; i < NN; i += 256)
      Ur[r * 2052 + i] = U[((size_t)b * O + o0 + r) * NN + i];
  __syncthreads();
  const float* Vb = V + ((size_t)b * O + o0) * NN;
  const int* ib = idx + (size_t)b * NN * KK;
  float s0 = 0, s1 = 0, s2 = 0, s3 = 0, c0 = 0, c1 = 0, c2 = 0, c3 = 0;
  for (int n = t; n < NN; n += 256) {
    float v0 = Vb[n], v1 = Vb[NN + n], v2 = Vb[2 * NN + n], v3 = Vb[3 * NN + n];
    const int* ip = ib + (size_t)n * KK;
#pragma unroll
    for (int j = 0; j < KK; j++) {
      int m = ip[j];
      float y0 = Ur[m] + v0, y1 = Ur[2052 + m] + v1;
      float y2 = Ur[4104 + m] + v2, y3 = Ur[6156 + m] + v3;
      s0 += y0; c0 = fmaf(y0, y0, c0);
      s1 += y1; c1 = fmaf(y1, y1, c1);
      s2 += y2; c2 = fmaf(y2, y2, c2);
      s3 += y3; c3 = fmaf(y3, y3, c3);
    }
  }
  float sa[4] = { s0, s1, s2, s3 }, ca[4] = { c0, c1, c2, c3 };
#pragma unroll
  for (int r = 0; r < 4; r++) {
    float a = sa[r], c = ca[r];
#pragma unroll
    for (int d = 1; d < 64; d <<= 1) { a += shflx_f(a, d); c += shflx_f(c, d); }
    if (lane == 0) { red[r][wave] = a; red[4 + r][wave] = c; }
  }
  __syncthreads();
  if (t < 4) {
    float a = red[t][0] + red[t][1] + red[t][2] + red[t][3];
    float c = red[4 + t][0] + red[4 + t][1] + red[4 + t][2] + red[4 + t][3];
    const float inv = 1.f / (float)(NN * KK);
    float mu = a * inv;
    float var = fmaxf(c * inv - mu * mu, 0.f);
    smv[t] = mu;
    smv[4 + t] = rsqrtf(var + EPSF);
  }
  __syncthreads();
  const float mu0 = smv[0], mu1 = smv[1], mu2 = smv[2], mu3 = smv[3];
  const float i0 = smv[4], i1 = smv[5], i2 = smv[6], i3 = smv[7];
  for (int n = t; n < NN; n += 256) {
    float v0 = Vb[n], v1 = Vb[NN + n], v2 = Vb[2 * NN + n], v3 = Vb[3 * NN + n];
    const int* ip = ib + (size_t)n * KK;
    float m0 = -3.4e38f, m1 = m0, m2 = m0, m3 = m0;
#pragma unroll
    for (int j = 0; j < KK; j++) {
      int m = ip[j];
      m0 = fmaxf(m0, Ur[m] + v0);
      m1 = fmaxf(m1, Ur[2052 + m] + v1);
      m2 = fmaxf(m2, Ur[4104 + m] + v2);
      m3 = fmaxf(m3, Ur[6156 + m] + v3);
    }
    float z;  // leaky-relu commutes with max (inv > 0)
    z = (m0 - mu0) * i0; xo[((size_t)b * 512 + o0 + 0) * NN + n] = z >= 0.f ? z : 0.2f * z;
    z = (m1 - mu1) * i1; xo[((size_t)b * 512 + o0 + 1) * NN + n] = z >= 0.f ? z : 0.2f * z;
    z = (m2 - mu2) * i2; xo[((size_t)b * 512 + o0 + 2) * NN + n] = z >= 0.f ? z : 0.2f * z;
    z = (m3 - mu3) * i3; xo[((size_t)b * 512 + o0 + 3) * NN + n] = z >= 0.f ? z : 0.2f * z;
  }
}

// ---------------- final 512x512 GEMM ----------------
__global__ __launch_bounds__(256) void y5_kernel(const float* __restrict__ xcat,
    const float* __restrict__ w5, float* __restrict__ y5)
{
  const int b = blockIdx.z;
  const int n = blockIdx.x * 64 + (threadIdx.x & 63);
  const int og = __builtin_amdgcn_readfirstlane(threadIdx.x >> 6);
  const int o0 = blockIdx.y * 32 + og * 8;
  const float* xb = xcat + (size_t)b * 512 * NN + n;
  const float* wr = w5 + (size_t)o0 * 512;
  float acc[8];
#pragma unroll
  for (int i = 0; i < 8; i++) acc[i] = 0.f;
  for (int c = 0; c < 512; c++) {
    float xv = xb[(size_t)c * NN];
#pragma unroll
    for (int i = 0; i < 8; i++) acc[i] = fmaf(wr[i * 512 + c], xv, acc[i]);
  }
#pragma unroll
  for (int i = 0; i < 8; i++) y5[((size_t)b * 512 + o0 + i) * NN + n] = acc[i];
}

__global__ __launch_bounds__(256) void bn5stat_kernel(const float* __restrict__ y5,
    float* __restrict__ bn5) {
  __shared__ float rs[4], rq[4];
  const int o = blockIdx.x, t = threadIdx.x, lane = t & 63, wave = t >> 6;
  float s = 0.f, q = 0.f;
  for (int b = 0; b < NB; b++) {
    const float* p = y5 + ((size_t)b * 512 + o) * NN;
    for (int n = t; n < NN; n += 256) { float v = p[n]; s += v; q = fmaf(v, v, q); }
  }
#pragma unroll
  for (int d = 1; d < 64; d <<= 1) { s += shflx_f(s, d); q += shflx_f(q, d); }
  if (lane == 0) { rs[wave] = s; rq[wave] = q; }
  __syncthreads();
  if (t == 0) {
    float S = rs[0] + rs[1] + rs[2] + rs[3];
    float Q = rq[0] + rq[1] + rq[2] + rq[3];
    const float inv = 1.f / (float)(NB * NN);
    float mu = S * inv;
    float var = fmaxf(Q * inv - mu * mu, 0.f);
    bn5[o] = mu;
    bn5[512 + o] = rsqrtf(var + EPSF);
  }
}

__global__ __launch_bounds__(256) void final_kernel(const float* __restrict__ y5,
    const float* __restrict__ bn5, const float* __restrict__ gamma,
    const float* __restrict__ beta, float* __restrict__ out)
{
  __shared__ float rm[4], rs[4];
  const int o = blockIdx.x, b = blockIdx.y, t = threadIdx.x, lane = t & 63, wave = t >> 6;
  const float mu = bn5[o], iv = bn5[512 + o], g = gamma[o], be = beta[o];
  const float* p = y5 + ((size_t)b * 512 + o) * NN;
  float mx = -3.4e38f, sm = 0.f;
  for (int n = t; n < NN; n += 256) {
    float z = (p[n] - mu) * iv;
    z = z * g + be;
    z = (z >= 0.f) ? z : 0.2f * z;
    mx = fmaxf(mx, z);
    sm += z;
  }
#pragma unroll
  for (int d = 1; d < 64; d <<= 1) { mx = fmaxf(mx, shflx_f(mx, d)); sm += shflx_f(sm, d); }
  if (lane == 0) { rm[wave] = mx; rs[wave] = sm; }
  __syncthreads();
  if (t == 0) {
    float M = fmaxf(fmaxf(rm[0], rm[1]), fmaxf(rm[2], rm[3]));
    float S = rs[0] + rs[1] + rs[2] + rs[3];
    out[(size_t)b * 1024 + o] = M;
    out[(size_t)b * 1024 + 512 + o] = S * (1.f / NN);
  }
}

extern "C" void kernel_launch(void* const* d_in, const int* in_sizes, int n_in,
                              void* d_out, int out_size, void* d_ws, size_t ws_size,
                              hipStream_t stream)
{
  (void)in_sizes; (void)n_in; (void)out_size; (void)ws_size;
  const float* x  = (const float*)d_in[0];
  const float* w1 = (const float*)d_in[1];
  const float* w2 = (const float*)d_in[2];
  const float* w3 = (const float*)d_in[3];
  const float* w4 = (const float*)d_in[4];
  const float* w5 = (const float*)d_in[5];
  const float* g5 = (const float*)d_in[6];
  const float* b5 = (const float*)d_in[7];
  float* out = (float*)d_out;

  // workspace layout (~137 MB)
  float* ws   = (float*)d_ws;
  float* xcat = ws;                         // 16*512*2048
  float* Ub   = xcat + 16777216;            // 16*256*2048
  float* Vb   = Ub + 8388608;               // 16*256*2048
  int*   idxb = (int*)(Vb + 8388608);       // 16*2048*20
  float* xxb  = (float*)(idxb + 655360);    // 16*2048
  float* bn5  = xxb + 32768;                // 1024
  float* y5   = Ub;                         // reuse U/V space after layer 4
  // f16 fragment buffers alias Vb: written by prep, consumed by knn, then
  // clobbered by uv (stream-ordered, safe). 16*2048*128 halves each = 16.8 MB.
  _Float16* xth = (_Float16*)Vb;
  _Float16* xtl = xth + (size_t)NB * NN * 128;

  struct Lyr { const float* xin; long bstride; int C, KB, O, coff; const float* w; };
  const Lyr L[4] = {
    { x,              3L * NN,   3,   1, 64,  0,   w1 },
    { xcat,           512L * NN, 64,  2, 64,  64,  w2 },
    { xcat + 64 * NN, 512L * NN, 64,  2, 128, 128, w3 },
    { xcat + 128 * NN,512L * NN, 128, 4, 256, 256, w4 },
  };

  for (int l = 0; l < 4; l++) {
    prep_kernel<<<dim3(NN / 256, NB), 256, 0, stream>>>(L[l].xin, xth, xtl, xxb,
                                                        L[l].C, L[l].KB, L[l].bstride);
    switch (L[l].KB) {
      case 1: knn_mfma<1><<<dim3(NN / 64, NB), 256, 0, stream>>>(xth, xtl, xxb, idxb); break;
      case 2: knn_mfma<2><<<dim3(NN / 64, NB), 256, 0, stream>>>(xth, xtl, xxb, idxb); break;
      default: knn_mfma<4><<<dim3(NN / 64, NB), 256, 0, stream>>>(xth, xtl, xxb, idxb); break;
    }
    uv_kernel<<<dim3(NN / 64, L[l].O / 32, NB), 256, 0, stream>>>(L[l].xin, L[l].w, Ub, Vb,
                                                                  L[l].C, L[l].O, L[l].bstride);
    edge_kernel<<<dim3(L[l].O / 4, NB), 256, 0, stream>>>(Ub, Vb, idxb,
                                                          xcat + (size_t)L[l].coff * NN, L[l].O);
  }
  y5_kernel<<<dim3(NN / 64, 16, NB), 256, 0, stream>>>(xcat, w5, y5);
  bn5stat_kernel<<<512, 256, 0, stream>>>(y5, bn5);
  final_kernel<<<dim3(512, NB), 256, 0, stream>>>(y5, bn5, g5, b5, out);
}

// Round 4
// 2257.860 us; speedup vs baseline: 1.6989x; 1.0226x over previous
//
#include <hip/hip_runtime.h>

#define NN 2048      // points
#define NB 16        // batch
#define KK 20        // k neighbors
#define EPSF 1e-5f

typedef unsigned long long ull;
typedef _Float16 v8h __attribute__((ext_vector_type(8)));
typedef float v4f __attribute__((ext_vector_type(4)));

__device__ __forceinline__ float shflx_f(float v, int m) { return __shfl_xor(v, m, 64); }
__device__ __forceinline__ ull shflx_u64(ull v, int m) {
  int lo = __shfl_xor((int)(unsigned)v, m, 64);
  int hi = __shfl_xor((int)(unsigned)(v >> 32), m, 64);
  return (((ull)(unsigned)hi) << 32) | (unsigned)lo;
}
__device__ __forceinline__ ull packkey(float s, int n) {
  unsigned u = __float_as_uint(s);
  u = (u & 0x80000000u) ? ~u : (u | 0x80000000u);
  return (((ull)u) << 32) | (unsigned)(2047 - n);   // ties -> lowest index wins under max
}

// ---------------- prep: x[C][N] fp32 -> fragment-ready f16 hi/lo [n][Cp] + xx ----
__global__ __launch_bounds__(256) void prep_kernel(const float* __restrict__ x,
    _Float16* __restrict__ xh, _Float16* __restrict__ xl, float* __restrict__ xx,
    int C, int KB, long bstride)
{
  const int b = blockIdx.y;
  const int n = blockIdx.x * 256 + threadIdx.x;
  const float* xb = x + (size_t)b * bstride;
  const int Cp = KB * 32;
  _Float16* ph = xh + ((size_t)b * NN + n) * Cp;
  _Float16* pl = xl + ((size_t)b * NN + n) * Cp;
  float s = 0.f;
  for (int kb = 0; kb < KB; kb++) {
    for (int g = 0; g < 4; g++) {
      v8h hv, lv;
#pragma unroll
      for (int j = 0; j < 8; j++) {
        int c = kb * 32 + g * 8 + j;
        float v = (c < C) ? xb[(size_t)c * NN + n] : 0.f;
        _Float16 h = (_Float16)v;
        hv[j] = h;
        lv[j] = (_Float16)(v - (float)h);
        s = fmaf(v, v, s);
      }
      *(v8h*)(ph + kb * 32 + g * 8) = hv;
      *(v8h*)(pl + kb * 32 + g * 8) = lv;
    }
  }
  xx[b * NN + n] = s;
}

// ---------------- tile scorer: 64 queries (4 A-tiles) x 16 candidates ----------
// s = Ah*Bh + Ah*Bl + Al*Bh (ll term ~2^-22 relative, below fp32 noise).
// Deterministic: identical code path in pass 1 and pass 2 -> bitwise-equal.
template<int KB>
__device__ __forceinline__ void tile_scores(const v8h (&Bh)[KB], const v8h (&Bl)[KB],
    const v8h (&Ah)[4][KB], const v8h (&Al)[4][KB], float xv, v4f (&out)[4])
{
#pragma unroll
  for (int a = 0; a < 4; a++) {
    v4f a0 = {0.f, 0.f, 0.f, 0.f};
    v4f a1 = {0.f, 0.f, 0.f, 0.f};
#pragma unroll
    for (int kb = 0; kb < KB; kb++) {
      v4f& acc = (kb & 1) ? a1 : a0;
      acc = __builtin_amdgcn_mfma_f32_16x16x32_f16(Ah[a][kb], Bh[kb], acc, 0, 0, 0);
      acc = __builtin_amdgcn_mfma_f32_16x16x32_f16(Ah[a][kb], Bl[kb], acc, 0, 0, 0);
      acc = __builtin_amdgcn_mfma_f32_16x16x32_f16(Al[a][kb], Bh[kb], acc, 0, 0, 0);
    }
    v4f s = a0 + a1;
#pragma unroll
    for (int j = 0; j < 4; j++) out[a][j] = s[j] - 0.5f * xv;
  }
}

// ---------------- kNN stage 1: per-(query, 1024-cand chunk) survivor lists ----
// 64 q/wave, 256 q/block, 2 chunks, 1024 jobs = 1 wave/SIMD device-wide.
// Pass 1: 32 group-maxima/query (col x tile-parity) -> tau = rank-19 <= t20.
// Pass 2: bitwise-identical rescore; survivors >= tau -> global list (cap 64,
// real count recorded; merge kernel has exact fallback on overflow).
template<int KB>
__global__ __launch_bounds__(256, 1) void knn2(
    const _Float16* __restrict__ xh, const _Float16* __restrict__ xl,
    const float* __restrict__ xxg, ull* __restrict__ slistG, int* __restrict__ cntG)
{
  __shared__ float gmL[256][33];
  __shared__ float tauL[256];
  __shared__ int scnt[256];

  const int t = threadIdx.x;
  const int lane = t & 63;
  const int wave = t >> 6;
  const int col = lane & 15;
  const int quad = lane >> 4;
  const int quad8 = quad * 8;
  const int b = blockIdx.x >> 1;
  const int chunk = blockIdx.x & 1;
  const int qg = blockIdx.y;
  const int Cp = KB * 32;
  const int cb = chunk * 1024;
  const _Float16* xhb = xh + (size_t)b * NN * Cp;
  const _Float16* xlb = xl + (size_t)b * NN * Cp;
  const float* xxb = xxg + b * NN;

  // A fragments: this wave's 64 queries (4 tiles of 16 rows)
  v8h Ah[4][KB], Al[4][KB];
  const int qw = qg * 256 + wave * 64;
#pragma unroll
  for (int a = 0; a < 4; a++) {
    const _Float16* pa = xhb + (size_t)(qw + a * 16 + col) * Cp + quad8;
    const _Float16* pb = xlb + (size_t)(qw + a * 16 + col) * Cp + quad8;
#pragma unroll
    for (int kb = 0; kb < KB; kb++) {
      Ah[a][kb] = *(const v8h*)(pa + kb * 32);
      Al[a][kb] = *(const v8h*)(pb + kb * 32);
    }
  }

  v8h Bh[2][KB], Bl[2][KB];
  float xvb[2];
  auto loadB = [&](int slot, int tt) {
    int t2 = tt < 63 ? tt : 63;
    int n = cb + t2 * 16 + col;
    const _Float16* pb = xhb + (size_t)n * Cp + quad8;
    const _Float16* pl = xlb + (size_t)n * Cp + quad8;
#pragma unroll
    for (int kb = 0; kb < KB; kb++) {
      Bh[slot][kb] = *(const v8h*)(pb + kb * 32);
      Bl[slot][kb] = *(const v8h*)(pl + kb * 32);
    }
    xvb[slot] = xxb[n];
  };

  // ---- pass 1: group maxima ----
  float gm[4][8];
#pragma unroll
  for (int a = 0; a < 4; a++)
#pragma unroll
    for (int j = 0; j < 8; j++) gm[a][j] = -3.4e38f;

  loadB(0, 0);
  for (int tt = 0; tt < 64; tt += 2) {
    loadB(1, tt + 1);
    {
      v4f out[4];
      tile_scores<KB>(Bh[0], Bl[0], Ah, Al, xvb[0], out);
#pragma unroll
      for (int a = 0; a < 4; a++)
#pragma unroll
        for (int j = 0; j < 4; j++) gm[a][j * 2] = fmaxf(gm[a][j * 2], out[a][j]);
    }
    loadB(0, tt + 2);
    {
      v4f out[4];
      tile_scores<KB>(Bh[1], Bl[1], Ah, Al, xvb[1], out);
#pragma unroll
      for (int a = 0; a < 4; a++)
#pragma unroll
        for (int j = 0; j < 4; j++) gm[a][j * 2 + 1] = fmaxf(gm[a][j * 2 + 1], out[a][j]);
    }
  }

  // write group maxima; queries are wave-private so no barrier, just lgkm drain
#pragma unroll
  for (int a = 0; a < 4; a++)
#pragma unroll
    for (int j = 0; j < 4; j++) {
      int qi = wave * 64 + a * 16 + quad * 4 + j;
      gmL[qi][col * 2 + 0] = gm[a][j * 2 + 0];
      gmL[qi][col * 2 + 1] = gm[a][j * 2 + 1];
    }
  scnt[t] = 0;
  asm volatile("s_waitcnt lgkmcnt(0)" ::: "memory");

  // tau = rank-19 of 32 group maxima (2 queries per round, 32-wide bitonic)
  for (int r = 0; r < 32; r++) {
    const int q = wave * 64 + r * 2 + (lane >> 5);
    const int idx = lane & 31;
    float v = gmL[q][idx];
#pragma unroll
    for (int kk = 2; kk <= 32; kk <<= 1) {
#pragma unroll
      for (int m = kk >> 1; m >= 1; m >>= 1) {
        float o = shflx_f(v, m);
        bool keepmax = ((idx & kk) == 0) == ((idx & m) == 0);
        v = keepmax ? fmaxf(v, o) : fminf(v, o);
      }
    }
    if (idx == 19) tauL[q] = v;
  }
  asm volatile("s_waitcnt lgkmcnt(0)" ::: "memory");

  float tq[4][4];
#pragma unroll
  for (int a = 0; a < 4; a++)
#pragma unroll
    for (int j = 0; j < 4; j++) tq[a][j] = tauL[wave * 64 + a * 16 + quad * 4 + j];

  // ---- pass 2: rescore + compact survivors to global ----
  ull* slB = slistG + (((size_t)b * NN + qg * 256) * 2 + chunk) * 64;
  loadB(0, 0);
  for (int tt = 0; tt < 64; tt += 2) {
    loadB(1, tt + 1);
    for (int s = 0; s < 2; s++) {
      v4f out[4];
      tile_scores<KB>(s ? Bh[1] : Bh[0], s ? Bl[1] : Bl[0], Ah, Al, xvb[s], out);
      int n = cb + (tt + s) * 16 + col;
#pragma unroll
      for (int a = 0; a < 4; a++)
#pragma unroll
        for (int j = 0; j < 4; j++) {
          float sc = out[a][j];
          if (sc >= tq[a][j]) {
            int qi = wave * 64 + a * 16 + quad * 4 + j;
            int pos = atomicAdd(&scnt[qi], 1);
            if (pos < 64) slB[(size_t)qi * 128 + pos] = packkey(sc, n);
          }
        }
      if (s == 0) loadB(0, tt + 2);
    }
  }
  asm volatile("s_waitcnt lgkmcnt(0)" ::: "memory");
  cntG[((size_t)b * NN + qg * 256 + t) * 2 + chunk] = scnt[t];
}

// ---------------- kNN stage 2: merge 2 chunk survivor lists -> top-20 --------
__global__ __launch_bounds__(256) void knn_merge(const ull* __restrict__ slistG,
    const int* __restrict__ cntG, const _Float16* __restrict__ xh,
    const _Float16* __restrict__ xl, const float* __restrict__ xxg,
    int* __restrict__ idxout, int Cp, int C)
{
  const int lane = threadIdx.x & 63, wave = threadIdx.x >> 6;
  const int b = blockIdx.y;
  const int q = blockIdx.x * 4 + wave;
  const int c0 = cntG[((size_t)b * NN + q) * 2 + 0];
  const int c1 = cntG[((size_t)b * NN + q) * 2 + 1];
  int* op = idxout + ((size_t)b * NN + q) * KK;

  if (c0 <= 64 && c1 <= 64) {
    const ull* s0 = slistG + ((size_t)b * NN + q) * 128;
    const int total = c0 + c1;
    ull e0 = 0, e1 = 0;
    int p0 = lane, p1 = lane + 64;
    if (p0 < total) e0 = (p0 < c0) ? s0[p0] : s0[64 + p0 - c0];
    if (p1 < total) e1 = (p1 < c0) ? s0[p1] : s0[64 + p1 - c0];
    for (int s = 0; s < KK; s++) {
      ull m = e0 > e1 ? e0 : e1;
      ull g = m;
#pragma unroll
      for (int d = 1; d < 64; d <<= 1) { ull o = shflx_u64(g, d); g = o > g ? o : g; }
      if (lane == 0) op[s] = 2047 - (int)(g & 0xFFFFFFFFu);
      if (e0 == g) e0 = 0; else if (e1 == g) e1 = 0;
    }
  } else {
    // exact fallback (survivor cap overflow — expected never): full fp32 rescan
    const _Float16* qh = xh + ((size_t)b * NN + q) * Cp;
    const _Float16* ql = xl + ((size_t)b * NN + q) * Cp;
    const float* xxb = xxg + b * NN;
    float sc[32];
#pragma unroll
    for (int i = 0; i < 32; i++) sc[i] = -0.5f * xxb[lane + 64 * i];
    for (int c = 0; c < C; c++) {
      float qv = (float)qh[c] + (float)ql[c];
      for (int i = 0; i < 32; i++) {
        int n = lane + 64 * i;
        float bv = (float)xh[((size_t)b * NN + n) * Cp + c] + (float)xl[((size_t)b * NN + n) * Cp + c];
        sc[i] = fmaf(qv, bv, sc[i]);
      }
    }
    for (int s = 0; s < KK; s++) {
      ull m = 0; int mi = -1;
      for (int i = 0; i < 32; i++) {
        ull k = packkey(sc[i], lane + 64 * i);
        if (k > m) { m = k; mi = i; }
      }
      ull g = m;
#pragma unroll
      for (int d = 1; d < 64; d <<= 1) { ull o = shflx_u64(g, d); g = o > g ? o : g; }
      if (lane == 0) op[s] = 2047 - (int)(g & 0xFFFFFFFFu);
      if (m == g && mi >= 0) sc[mi] = -3.4e38f;
    }
  }
}

// ---------------- U = Wa*x, V = (Wb-Wa)*x ----------------
__global__ __launch_bounds__(256) void uv_kernel(const float* __restrict__ xin,
    const float* __restrict__ w, float* __restrict__ U, float* __restrict__ V,
    int C, int O, long bstride)
{
  const int b = blockIdx.z;
  const int n = blockIdx.x * 64 + (threadIdx.x & 63);
  const int og = __builtin_amdgcn_readfirstlane(threadIdx.x >> 6);  // wave-uniform -> s_loads for w
  const int o0 = blockIdx.y * 32 + og * 8;
  const float* xb = xin + (size_t)b * bstride + n;
  const float* wa = w + (size_t)o0 * 2 * C;
  float au[8], ab[8];
#pragma unroll
  for (int i = 0; i < 8; i++) { au[i] = 0.f; ab[i] = 0.f; }
  for (int c = 0; c < C; c++) {
    float xv = xb[(size_t)c * NN];
#pragma unroll
    for (int i = 0; i < 8; i++) {
      au[i] = fmaf(wa[i * 2 * C + c], xv, au[i]);
      ab[i] = fmaf(wa[i * 2 * C + C + c], xv, ab[i]);
    }
  }
#pragma unroll
  for (int i = 0; i < 8; i++) {
    size_t base = ((size_t)b * O + o0 + i) * NN + n;
    U[base] = au[i];
    V[base] = ab[i] - au[i];
  }
}

// ---------------- edge aggregation: stats + normalized max-over-k ----------------
__global__ __launch_bounds__(256) void edge_kernel(const float* __restrict__ U,
    const float* __restrict__ V, const int* __restrict__ idx,
    float* __restrict__ xo, int O)
{
  __shared__ float Ur[4 * 2052];   // +4 pad breaks the i-stride bank collision
  __shared__ float red[8][4];
  __shared__ float smv[8];
  const int b = blockIdx.y, o0 = blockIdx.x * 4;
  const int t = threadIdx.x, lane = t & 63, wave = t >> 6;
  for (int r = 0; r < 4; r++)
    for (int i = t; i < NN; i += 256)
      Ur[r * 2052 + i] = U[((size_t)b * O + o0 + r) * NN + i];
  __syncthreads();
  const float* Vb = V + ((size_t)b * O + o0) * NN;
  const int* ib = idx + (size_t)b * NN * KK;
  float s0 = 0, s1 = 0, s2 = 0, s3 = 0, c0 = 0, c1 = 0, c2 = 0, c3 = 0;
  for (int n = t; n < NN; n += 256) {
    float v0 = Vb[n], v1 = Vb[NN + n], v2 = Vb[2 * NN + n], v3 = Vb[3 * NN + n];
    const int* ip = ib + (size_t)n * KK;
#pragma unroll
    for (int j = 0; j < KK; j++) {
      int m = ip[j];
      float y0 = Ur[m] + v0, y1 = Ur[2052 + m] + v1;
      float y2 = Ur[4104 + m] + v2, y3 = Ur[6156 + m] + v3;
      s0 += y0; c0 = fmaf(y0, y0, c0);
      s1 += y1; c1 = fmaf(y1, y1, c1);
      s2 += y2; c2 = fmaf(y2, y2, c2);
      s3 += y3; c3 = fmaf(y3, y3, c3);
    }
  }
  float sa[4] = { s0, s1, s2, s3 }, ca[4] = { c0, c1, c2, c3 };
#pragma unroll
  for (int r = 0; r < 4; r++) {
    float a = sa[r], c = ca[r];
#pragma unroll
    for (int d = 1; d < 64; d <<= 1) { a += shflx_f(a, d); c += shflx_f(c, d); }
    if (lane == 0) { red[r][wave] = a; red[4 + r][wave] = c; }
  }
  __syncthreads();
  if (t < 4) {
    float a = red[t][0] + red[t][1] + red[t][2] + red[t][3];
    float c = red[4 + t][0] + red[4 + t][1] + red[4 + t][2] + red[4 + t][3];
    const float inv = 1.f / (float)(NN * KK);
    float mu = a * inv;
    float var = fmaxf(c * inv - mu * mu, 0.f);
    smv[t] = mu;
    smv[4 + t] = rsqrtf(var + EPSF);
  }
  __syncthreads();
  const float mu0 = smv[0], mu1 = smv[1], mu2 = smv[2], mu3 = smv[3];
  const float i0 = smv[4], i1 = smv[5], i2 = smv[6], i3 = smv[7];
  for (int n = t; n < NN; n += 256) {
    float v0 = Vb[n], v1 = Vb[NN + n], v2 = Vb[2 * NN + n], v3 = Vb[3 * NN + n];
    const int* ip = ib + (size_t)n * KK;
    float m0 = -3.4e38f, m1 = m0, m2 = m0, m3 = m0;
#pragma unroll
    for (int j = 0; j < KK; j++) {
      int m = ip[j];
      m0 = fmaxf(m0, Ur[m] + v0);
      m1 = fmaxf(m1, Ur[2052 + m] + v1);
      m2 = fmaxf(m2, Ur[4104 + m] + v2);
      m3 = fmaxf(m3, Ur[6156 + m] + v3);
    }
    float z;  // leaky-relu commutes with max (inv > 0)
    z = (m0 - mu0) * i0; xo[((size_t)b * 512 + o0 + 0) * NN + n] = z >= 0.f ? z : 0.2f * z;
    z = (m1 - mu1) * i1; xo[((size_t)b * 512 + o0 + 1) * NN + n] = z >= 0.f ? z : 0.2f * z;
    z = (m2 - mu2) * i2; xo[((size_t)b * 512 + o0 + 2) * NN + n] = z >= 0.f ? z : 0.2f * z;
    z = (m3 - mu3) * i3; xo[((size_t)b * 512 + o0 + 3) * NN + n] = z >= 0.f ? z : 0.2f * z;
  }
}

// ---------------- final 512x512 GEMM ----------------
__global__ __launch_bounds__(256) void y5_kernel(const float* __restrict__ xcat,
    const float* __restrict__ w5, float* __restrict__ y5)
{
  const int b = blockIdx.z;
  const int n = blockIdx.x * 64 + (threadIdx.x & 63);
  const int og = __builtin_amdgcn_readfirstlane(threadIdx.x >> 6);
  const int o0 = blockIdx.y * 32 + og * 8;
  const float* xb = xcat + (size_t)b * 512 * NN + n;
  const float* wr = w5 + (size_t)o0 * 512;
  float acc[8];
#pragma unroll
  for (int i = 0; i < 8; i++) acc[i] = 0.f;
  for (int c = 0; c < 512; c++) {
    float xv = xb[(size_t)c * NN];
#pragma unroll
    for (int i = 0; i < 8; i++) acc[i] = fmaf(wr[i * 512 + c], xv, acc[i]);
  }
#pragma unroll
  for (int i = 0; i < 8; i++) y5[((size_t)b * 512 + o0 + i) * NN + n] = acc[i];
}

__global__ __launch_bounds__(256) void bn5stat_kernel(const float* __restrict__ y5,
    float* __restrict__ bn5) {
  __shared__ float rs[4], rq[4];
  const int o = blockIdx.x, t = threadIdx.x, lane = t & 63, wave = t >> 6;
  float s = 0.f, q = 0.f;
  for (int b = 0; b < NB; b++) {
    const float* p = y5 + ((size_t)b * 512 + o) * NN;
    for (int n = t; n < NN; n += 256) { float v = p[n]; s += v; q = fmaf(v, v, q); }
  }
#pragma unroll
  for (int d = 1; d < 64; d <<= 1) { s += shflx_f(s, d); q += shflx_f(q, d); }
  if (lane == 0) { rs[wave] = s; rq[wave] = q; }
  __syncthreads();
  if (t == 0) {
    float S = rs[0] + rs[1] + rs[2] + rs[3];
    float Q = rq[0] + rq[1] + rq[2] + rq[3];
    const float inv = 1.f / (float)(NB * NN);
    float mu = S * inv;
    float var = fmaxf(Q * inv - mu * mu, 0.f);
    bn5[o] = mu;
    bn5[512 + o] = rsqrtf(var + EPSF);
  }
}

__global__ __launch_bounds__(256) void final_kernel(const float* __restrict__ y5,
    const float* __restrict__ bn5, const float* __restrict__ gamma,
    const float* __restrict__ beta, float* __restrict__ out)
{
  __shared__ float rm[4], rs[4];
  const int o = blockIdx.x, b = blockIdx.y, t = threadIdx.x, lane = t & 63, wave = t >> 6;
  const float mu = bn5[o], iv = bn5[512 + o], g = gamma[o], be = beta[o];
  const float* p = y5 + ((size_t)b * 512 + o) * NN;
  float mx = -3.4e38f, sm = 0.f;
  for (int n = t; n < NN; n += 256) {
    float z = (p[n] - mu) * iv;
    z = z * g + be;
    z = (z >= 0.f) ? z : 0.2f * z;
    mx = fmaxf(mx, z);
    sm += z;
  }
#pragma unroll
  for (int d = 1; d < 64; d <<= 1) { mx = fmaxf(mx, shflx_f(mx, d)); sm += shflx_f(sm, d); }
  if (lane == 0) { rm[wave] = mx; rs[wave] = sm; }
  __syncthreads();
  if (t == 0) {
    float M = fmaxf(fmaxf(rm[0], rm[1]), fmaxf(rm[2], rm[3]));
    float S = rs[0] + rs[1] + rs[2] + rs[3];
    out[(size_t)b * 1024 + o] = M;
    out[(size_t)b * 1024 + 512 + o] = S * (1.f / NN);
  }
}

extern "C" void kernel_launch(void* const* d_in, const int* in_sizes, int n_in,
                              void* d_out, int out_size, void* d_ws, size_t ws_size,
                              hipStream_t stream)
{
  (void)in_sizes; (void)n_in; (void)out_size; (void)ws_size;
  const float* x  = (const float*)d_in[0];
  const float* w1 = (const float*)d_in[1];
  const float* w2 = (const float*)d_in[2];
  const float* w3 = (const float*)d_in[3];
  const float* w4 = (const float*)d_in[4];
  const float* w5 = (const float*)d_in[5];
  const float* g5 = (const float*)d_in[6];
  const float* b5 = (const float*)d_in[7];
  float* out = (float*)d_out;

  // workspace layout (~137 MB)
  float* ws   = (float*)d_ws;
  float* xcat = ws;                         // 16*512*2048
  float* Ub   = xcat + 16777216;            // 16*256*2048
  float* Vb   = Ub + 8388608;               // 16*256*2048
  int*   idxb = (int*)(Vb + 8388608);       // 16*2048*20
  float* xxb  = (float*)(idxb + 655360);    // 16*2048
  float* bn5  = xxb + 32768;                // 1024
  float* y5   = Ub;                         // reuse U/V space after layer 4
  // f16 fragment buffers alias Vb (prep -> knn2 -> merge, then uv clobbers Vb).
  _Float16* xth = (_Float16*)Vb;
  _Float16* xtl = xth + (size_t)NB * NN * 128;
  int* cntb = (int*)(xtl + (size_t)NB * NN * 128);   // 16*2048*2 ints, still inside Vb
  // survivor lists alias Ub: 16*2048*2*64 u64 = 33.55 MB = exactly Ub.
  ull* slist = (ull*)Ub;

  struct Lyr { const float* xin; long bstride; int C, KB, O, coff; const float* w; };
  const Lyr L[4] = {
    { x,              3L * NN,   3,   1, 64,  0,   w1 },
    { xcat,           512L * NN, 64,  2, 64,  64,  w2 },
    { xcat + 64 * NN, 512L * NN, 64,  2, 128, 128, w3 },
    { xcat + 128 * NN,512L * NN, 128, 4, 256, 256, w4 },
  };

  for (int l = 0; l < 4; l++) {
    prep_kernel<<<dim3(NN / 256, NB), 256, 0, stream>>>(L[l].xin, xth, xtl, xxb,
                                                        L[l].C, L[l].KB, L[l].bstride);
    // grid x = (b, chunk) so same-working-set blocks land on one XCD (L2 reuse)
    switch (L[l].KB) {
      case 1: knn2<1><<<dim3(NB * 2, NN / 256), 256, 0, stream>>>(xth, xtl, xxb, slist, cntb); break;
      case 2: knn2<2><<<dim3(NB * 2, NN / 256), 256, 0, stream>>>(xth, xtl, xxb, slist, cntb); break;
      default: knn2<4><<<dim3(NB * 2, NN / 256), 256, 0, stream>>>(xth, xtl, xxb, slist, cntb); break;
    }
    knn_merge<<<dim3(NN / 4, NB), 256, 0, stream>>>(slist, cntb, xth, xtl, xxb, idxb,
                                                    L[l].KB * 32, L[l].C);
    uv_kernel<<<dim3(NN / 64, L[l].O / 32, NB), 256, 0, stream>>>(L[l].xin, L[l].w, Ub, Vb,
                                                                  L[l].C, L[l].O, L[l].bstride);
    edge_kernel<<<dim3(L[l].O / 4, NB), 256, 0, stream>>>(Ub, Vb, idxb,
                                                          xcat + (size_t)L[l].coff * NN, L[l].O);
  }
  y5_kernel<<<dim3(NN / 64, 16, NB), 256, 0, stream>>>(xcat, w5, y5);
  bn5stat_kernel<<<512, 256, 0, stream>>>(y5, bn5);
  final_kernel<<<dim3(512, NB), 256, 0, stream>>>(y5, bn5, g5, b5, out);
}

// Round 6
// 1743.202 us; speedup vs baseline: 2.2005x; 1.2952x over previous
//
#include <hip/hip_runtime.h>

#define NN 2048      // points
#define NB 16        // batch
#define KK 20        // k neighbors
#define EPSF 1e-5f

typedef unsigned long long ull;
typedef _Float16 v8h __attribute__((ext_vector_type(8)));
typedef float v4f __attribute__((ext_vector_type(4)));

__device__ __forceinline__ float shflx_f(float v, int m) { return __shfl_xor(v, m, 64); }
__device__ __forceinline__ ull shflx_u64(ull v, int m) {
  int lo = __shfl_xor((int)(unsigned)v, m, 64);
  int hi = __shfl_xor((int)(unsigned)(v >> 32), m, 64);
  return (((ull)(unsigned)hi) << 32) | (unsigned)lo;
}
__device__ __forceinline__ ull packkey(float s, int n) {
  unsigned u = __float_as_uint(s);
  u = (u & 0x80000000u) ? ~u : (u | 0x80000000u);
  return (((ull)u) << 32) | (unsigned)(2047 - n);   // ties -> lowest index wins under max
}

// ---------------- prep: x[C][N] fp32 -> fragment-ready f16 hi/lo [n][Cp] + xx ----
__global__ __launch_bounds__(256) void prep_kernel(const float* __restrict__ x,
    _Float16* __restrict__ xh, _Float16* __restrict__ xl, float* __restrict__ xx,
    int C, int KB, long bstride)
{
  const int b = blockIdx.y;
  const int n = blockIdx.x * 256 + threadIdx.x;
  const float* xb = x + (size_t)b * bstride;
  const int Cp = KB * 32;
  _Float16* ph = xh + ((size_t)b * NN + n) * Cp;
  _Float16* pl = xl + ((size_t)b * NN + n) * Cp;
  float s = 0.f;
  for (int kb = 0; kb < KB; kb++) {
    for (int g = 0; g < 4; g++) {
      v8h hv, lv;
#pragma unroll
      for (int j = 0; j < 8; j++) {
        int c = kb * 32 + g * 8 + j;
        float v = (c < C) ? xb[(size_t)c * NN + n] : 0.f;
        _Float16 h = (_Float16)v;
        hv[j] = h;
        lv[j] = (_Float16)(v - (float)h);
        s = fmaf(v, v, s);
      }
      *(v8h*)(ph + kb * 32 + g * 8) = hv;
      *(v8h*)(pl + kb * 32 + g * 8) = lv;
    }
  }
  xx[b * NN + n] = s;
}

// ---------------- tile scorer: 64 queries (4 A-tiles) x 16 candidates ----------
template<int KB>
__device__ __forceinline__ void tile_scores(const v8h (&Bh)[KB], const v8h (&Bl)[KB],
    const v8h (&Ah)[4][KB], const v8h (&Al)[4][KB], float xv, v4f (&out)[4])
{
#pragma unroll
  for (int a = 0; a < 4; a++) {
    v4f a0 = {0.f, 0.f, 0.f, 0.f};
    v4f a1 = {0.f, 0.f, 0.f, 0.f};
#pragma unroll
    for (int kb = 0; kb < KB; kb++) {
      v4f& acc = (kb & 1) ? a1 : a0;
      acc = __builtin_amdgcn_mfma_f32_16x16x32_f16(Ah[a][kb], Bh[kb], acc, 0, 0, 0);
      acc = __builtin_amdgcn_mfma_f32_16x16x32_f16(Ah[a][kb], Bl[kb], acc, 0, 0, 0);
      acc = __builtin_amdgcn_mfma_f32_16x16x32_f16(Al[a][kb], Bh[kb], acc, 0, 0, 0);
    }
    v4f s = a0 + a1;
#pragma unroll
    for (int j = 0; j < 4; j++) out[a][j] = s[j] - 0.5f * xv;
  }
}

// ---------------- kNN stage 1: per-(query, 1024-cand chunk) survivor lists ----
template<int KB>
__global__ __launch_bounds__(256, 1) void knn2(
    const _Float16* __restrict__ xh, const _Float16* __restrict__ xl,
    const float* __restrict__ xxg, ull* __restrict__ slistG, int* __restrict__ cntG)
{
  __shared__ float gmL[256][33];
  __shared__ float tauL[256];
  __shared__ int scnt[256];

  const int t = threadIdx.x;
  const int lane = t & 63;
  const int wave = t >> 6;
  const int col = lane & 15;
  const int quad = lane >> 4;
  const int quad8 = quad * 8;
  const int b = blockIdx.x >> 1;
  const int chunk = blockIdx.x & 1;
  const int qg = blockIdx.y;
  const int Cp = KB * 32;
  const int cb = chunk * 1024;
  const _Float16* xhb = xh + (size_t)b * NN * Cp;
  const _Float16* xlb = xl + (size_t)b * NN * Cp;
  const float* xxb = xxg + b * NN;

  v8h Ah[4][KB], Al[4][KB];
  const int qw = qg * 256 + wave * 64;
#pragma unroll
  for (int a = 0; a < 4; a++) {
    const _Float16* pa = xhb + (size_t)(qw + a * 16 + col) * Cp + quad8;
    const _Float16* pb = xlb + (size_t)(qw + a * 16 + col) * Cp + quad8;
#pragma unroll
    for (int kb = 0; kb < KB; kb++) {
      Ah[a][kb] = *(const v8h*)(pa + kb * 32);
      Al[a][kb] = *(const v8h*)(pb + kb * 32);
    }
  }

  v8h Bh[2][KB], Bl[2][KB];
  float xvb[2];
  auto loadB = [&](int slot, int tt) {
    int t2 = tt < 63 ? tt : 63;
    int n = cb + t2 * 16 + col;
    const _Float16* pb = xhb + (size_t)n * Cp + quad8;
    const _Float16* pl = xlb + (size_t)n * Cp + quad8;
#pragma unroll
    for (int kb = 0; kb < KB; kb++) {
      Bh[slot][kb] = *(const v8h*)(pb + kb * 32);
      Bl[slot][kb] = *(const v8h*)(pl + kb * 32);
    }
    xvb[slot] = xxb[n];
  };

  float gm[4][8];
#pragma unroll
  for (int a = 0; a < 4; a++)
#pragma unroll
    for (int j = 0; j < 8; j++) gm[a][j] = -3.4e38f;

  loadB(0, 0);
  for (int tt = 0; tt < 64; tt += 2) {
    loadB(1, tt + 1);
    {
      v4f out[4];
      tile_scores<KB>(Bh[0], Bl[0], Ah, Al, xvb[0], out);
#pragma unroll
      for (int a = 0; a < 4; a++)
#pragma unroll
        for (int j = 0; j < 4; j++) gm[a][j * 2] = fmaxf(gm[a][j * 2], out[a][j]);
    }
    loadB(0, tt + 2);
    {
      v4f out[4];
      tile_scores<KB>(Bh[1], Bl[1], Ah, Al, xvb[1], out);
#pragma unroll
      for (int a = 0; a < 4; a++)
#pragma unroll
        for (int j = 0; j < 4; j++) gm[a][j * 2 + 1] = fmaxf(gm[a][j * 2 + 1], out[a][j]);
    }
  }

#pragma unroll
  for (int a = 0; a < 4; a++)
#pragma unroll
    for (int j = 0; j < 4; j++) {
      int qi = wave * 64 + a * 16 + quad * 4 + j;
      gmL[qi][col * 2 + 0] = gm[a][j * 2 + 0];
      gmL[qi][col * 2 + 1] = gm[a][j * 2 + 1];
    }
  scnt[t] = 0;
  asm volatile("s_waitcnt lgkmcnt(0)" ::: "memory");

  for (int r = 0; r < 32; r++) {
    const int q = wave * 64 + r * 2 + (lane >> 5);
    const int idx = lane & 31;
    float v = gmL[q][idx];
#pragma unroll
    for (int kk = 2; kk <= 32; kk <<= 1) {
#pragma unroll
      for (int m = kk >> 1; m >= 1; m >>= 1) {
        float o = shflx_f(v, m);
        bool keepmax = ((idx & kk) == 0) == ((idx & m) == 0);
        v = keepmax ? fmaxf(v, o) : fminf(v, o);
      }
    }
    if (idx == 19) tauL[q] = v;
  }
  asm volatile("s_waitcnt lgkmcnt(0)" ::: "memory");

  float tq[4][4];
#pragma unroll
  for (int a = 0; a < 4; a++)
#pragma unroll
    for (int j = 0; j < 4; j++) tq[a][j] = tauL[wave * 64 + a * 16 + quad * 4 + j];

  ull* slB = slistG + (((size_t)b * NN + qg * 256) * 2 + chunk) * 64;
  loadB(0, 0);
  for (int tt = 0; tt < 64; tt += 2) {
    loadB(1, tt + 1);
    for (int s = 0; s < 2; s++) {
      v4f out[4];
      tile_scores<KB>(s ? Bh[1] : Bh[0], s ? Bl[1] : Bl[0], Ah, Al, xvb[s], out);
      int n = cb + (tt + s) * 16 + col;
#pragma unroll
      for (int a = 0; a < 4; a++)
#pragma unroll
        for (int j = 0; j < 4; j++) {
          float sc = out[a][j];
          if (sc >= tq[a][j]) {
            int qi = wave * 64 + a * 16 + quad * 4 + j;
            int pos = atomicAdd(&scnt[qi], 1);
            if (pos < 64) slB[(size_t)qi * 128 + pos] = packkey(sc, n);
          }
        }
      if (s == 0) loadB(0, tt + 2);
    }
  }
  asm volatile("s_waitcnt lgkmcnt(0)" ::: "memory");
  cntG[((size_t)b * NN + qg * 256 + t) * 2 + chunk] = scnt[t];
}

// ---------------- kNN stage 2: merge 2 chunk survivor lists -> top-20 --------
__global__ __launch_bounds__(256) void knn_merge(const ull* __restrict__ slistG,
    const int* __restrict__ cntG, const _Float16* __restrict__ xh,
    const _Float16* __restrict__ xl, const float* __restrict__ xxg,
    int* __restrict__ idxout, int Cp, int C)
{
  const int lane = threadIdx.x & 63, wave = threadIdx.x >> 6;
  const int b = blockIdx.y;
  const int q = blockIdx.x * 4 + wave;
  const int c0 = cntG[((size_t)b * NN + q) * 2 + 0];
  const int c1 = cntG[((size_t)b * NN + q) * 2 + 1];
  int* op = idxout + ((size_t)b * NN + q) * KK;

  if (c0 <= 64 && c1 <= 64) {
    const ull* s0 = slistG + ((size_t)b * NN + q) * 128;
    const int total = c0 + c1;
    ull e0 = 0, e1 = 0;
    int p0 = lane, p1 = lane + 64;
    if (p0 < total) e0 = (p0 < c0) ? s0[p0] : s0[64 + p0 - c0];
    if (p1 < total) e1 = (p1 < c0) ? s0[p1] : s0[64 + p1 - c0];
    for (int s = 0; s < KK; s++) {
      ull m = e0 > e1 ? e0 : e1;
      ull g = m;
#pragma unroll
      for (int d = 1; d < 64; d <<= 1) { ull o = shflx_u64(g, d); g = o > g ? o : g; }
      if (lane == 0) op[s] = 2047 - (int)(g & 0xFFFFFFFFu);
      if (e0 == g) e0 = 0; else if (e1 == g) e1 = 0;
    }
  } else {
    // exact fallback (survivor cap overflow — expected never): full fp32 rescan
    const _Float16* qh = xh + ((size_t)b * NN + q) * Cp;
    const _Float16* ql = xl + ((size_t)b * NN + q) * Cp;
    const float* xxb = xxg + b * NN;
    float sc[32];
#pragma unroll
    for (int i = 0; i < 32; i++) sc[i] = -0.5f * xxb[lane + 64 * i];
    for (int c = 0; c < C; c++) {
      float qv = (float)qh[c] + (float)ql[c];
      for (int i = 0; i < 32; i++) {
        int n = lane + 64 * i;
        float bv = (float)xh[((size_t)b * NN + n) * Cp + c] + (float)xl[((size_t)b * NN + n) * Cp + c];
        sc[i] = fmaf(qv, bv, sc[i]);
      }
    }
    for (int s = 0; s < KK; s++) {
      ull m = 0; int mi = -1;
      for (int i = 0; i < 32; i++) {
        ull k = packkey(sc[i], lane + 64 * i);
        if (k > m) { m = k; mi = i; }
      }
      ull g = m;
#pragma unroll
      for (int d = 1; d < 64; d <<= 1) { ull o = shflx_u64(g, d); g = o > g ? o : g; }
      if (lane == 0) op[s] = 2047 - (int)(g & 0xFFFFFFFFu);
      if (m == g && mi >= 0) sc[mi] = -3.4e38f;
    }
  }
}

// ---------------- weight converts ----------------
__global__ __launch_bounds__(256) void wcvt_uv(const float* __restrict__ w,
    _Float16* __restrict__ wuh, _Float16* __restrict__ wul,
    _Float16* __restrict__ wvh, _Float16* __restrict__ wvl, int C, int Cp, int O)
{
  int idx = blockIdx.x * 256 + threadIdx.x;
  if (idx >= O * Cp) return;
  int o = idx / Cp, c = idx - o * Cp;
  float a = 0.f, bv = 0.f;
  if (c < C) { a = w[o * 2 * C + c]; bv = w[o * 2 * C + C + c]; }
  float v = bv - a;
  _Float16 ah = (_Float16)a; wuh[idx] = ah; wul[idx] = (_Float16)(a - (float)ah);
  _Float16 vh = (_Float16)v; wvh[idx] = vh; wvl[idx] = (_Float16)(v - (float)vh);
}

__global__ __launch_bounds__(256) void w5cvt(const float* __restrict__ w5,
    _Float16* __restrict__ w5h, _Float16* __restrict__ w5l)
{
  int idx = blockIdx.x * 256 + threadIdx.x;
  float v = w5[idx];
  _Float16 h = (_Float16)v;
  w5h[idx] = h;
  w5l[idx] = (_Float16)(v - (float)h);
}

// ---------------- xcat fp32 [b][c][n] -> f16 hi/lo fragments [b][kc][n][32] ----
__global__ __launch_bounds__(256) void y5cvt_kernel(const float* __restrict__ xcat,
    _Float16* __restrict__ xh, _Float16* __restrict__ xl)
{
  const int b = blockIdx.y;
  const int n = blockIdx.x * 256 + threadIdx.x;
  for (int kc = blockIdx.z * 4; kc < blockIdx.z * 4 + 4; kc++) {
    v8h h[4], l[4];
#pragma unroll
    for (int g = 0; g < 4; g++)
#pragma unroll
      for (int j = 0; j < 8; j++) {
        float v = xcat[((size_t)b * 512 + kc * 32 + g * 8 + j) * NN + n];
        _Float16 hh = (_Float16)v;
        h[g][j] = hh;
        l[g][j] = (_Float16)(v - (float)hh);
      }
    size_t base = (((size_t)b * 16 + kc) * NN + n) * 32;
#pragma unroll
    for (int g = 0; g < 4; g++) {
      *(v8h*)(xh + base + g * 8) = h[g];
      *(v8h*)(xl + base + g * 8) = l[g];
    }
  }
}

// ---------------- y5 = w5 * xcat via MFMA (f16 hi/lo 3-product) ----------------
__global__ __launch_bounds__(256) void y5_mfma(const _Float16* __restrict__ w5h,
    const _Float16* __restrict__ w5l, const _Float16* __restrict__ xh,
    const _Float16* __restrict__ xl, float* __restrict__ y5)
{
  const int lane = threadIdx.x & 63, wave = threadIdx.x >> 6;
  const int col = lane & 15, quad = lane >> 4, quad8 = quad * 8;
  const int b = blockIdx.z;
  const int o0 = blockIdx.x * 256 + wave * 64;
  const int nb0 = blockIdx.y * 128;
  v4f acc[4][8];
#pragma unroll
  for (int a = 0; a < 4; a++)
#pragma unroll
    for (int t = 0; t < 8; t++) acc[a][t] = {0.f, 0.f, 0.f, 0.f};

  for (int kc = 0; kc < 16; kc++) {
    v8h Ah[4], Al[4];
#pragma unroll
    for (int a = 0; a < 4; a++) {
      size_t off = (size_t)(o0 + a * 16 + col) * 512 + kc * 32 + quad8;
      Ah[a] = *(const v8h*)(w5h + off);
      Al[a] = *(const v8h*)(w5l + off);
    }
#pragma unroll
    for (int t = 0; t < 8; t++) {
      int n = nb0 + t * 16 + col;
      size_t boff = (((size_t)b * 16 + kc) * NN + n) * 32 + quad8;
      v8h Bh = *(const v8h*)(xh + boff);
      v8h Bl = *(const v8h*)(xl + boff);
#pragma unroll
      for (int a = 0; a < 4; a++) {
        acc[a][t] = __builtin_amdgcn_mfma_f32_16x16x32_f16(Ah[a], Bh, acc[a][t], 0, 0, 0);
        acc[a][t] = __builtin_amdgcn_mfma_f32_16x16x32_f16(Ah[a], Bl, acc[a][t], 0, 0, 0);
        acc[a][t] = __builtin_amdgcn_mfma_f32_16x16x32_f16(Al[a], Bh, acc[a][t], 0, 0, 0);
      }
    }
  }
#pragma unroll
  for (int a = 0; a < 4; a++)
#pragma unroll
    for (int t = 0; t < 8; t++)
#pragma unroll
      for (int j = 0; j < 4; j++)
        y5[((size_t)b * 512 + o0 + a * 16 + quad * 4 + j) * NN + nb0 + t * 16 + col] = acc[a][t][j];
}

// ---------------- U/V chunk (64 out-ch) via MFMA: U = Wa*x, V = (Wb-Wa)*x ------
// Writes chunk-local buffers Uc/Vc laid out [b][64][NN]; weights pre-offset.
__global__ __launch_bounds__(256) void uv_mfma(const _Float16* __restrict__ wuh,
    const _Float16* __restrict__ wul, const _Float16* __restrict__ wvh,
    const _Float16* __restrict__ wvl, const _Float16* __restrict__ xh,
    const _Float16* __restrict__ xl, float* __restrict__ Uc, float* __restrict__ Vc,
    int Cp)
{
  const int lane = threadIdx.x & 63, wave = threadIdx.x >> 6;
  const int col = lane & 15, quad = lane >> 4, quad8 = quad * 8;
  const int b = blockIdx.z;
  const int o0 = blockIdx.x * 32;           // chunk-local out channel base
  const int nb0 = blockIdx.y * 512 + wave * 128;
  v4f aU[2][8], aV[2][8];
#pragma unroll
  for (int a = 0; a < 2; a++)
#pragma unroll
    for (int t = 0; t < 8; t++) { aU[a][t] = {0.f,0.f,0.f,0.f}; aV[a][t] = {0.f,0.f,0.f,0.f}; }

  const int KBr = Cp >> 5;
  for (int kb = 0; kb < KBr; kb++) {
    v8h Uh[2], Ul[2], Vh[2], Vl[2];
#pragma unroll
    for (int a = 0; a < 2; a++) {
      size_t off = (size_t)(o0 + a * 16 + col) * Cp + kb * 32 + quad8;
      Uh[a] = *(const v8h*)(wuh + off);
      Ul[a] = *(const v8h*)(wul + off);
      Vh[a] = *(const v8h*)(wvh + off);
      Vl[a] = *(const v8h*)(wvl + off);
    }
#pragma unroll
    for (int t = 0; t < 8; t++) {
      int n = nb0 + t * 16 + col;
      size_t boff = ((size_t)b * NN + n) * Cp + kb * 32 + quad8;
      v8h Bh = *(const v8h*)(xh + boff);
      v8h Bl = *(const v8h*)(xl + boff);
#pragma unroll
      for (int a = 0; a < 2; a++) {
        aU[a][t] = __builtin_amdgcn_mfma_f32_16x16x32_f16(Uh[a], Bh, aU[a][t], 0, 0, 0);
        aU[a][t] = __builtin_amdgcn_mfma_f32_16x16x32_f16(Uh[a], Bl, aU[a][t], 0, 0, 0);
        aU[a][t] = __builtin_amdgcn_mfma_f32_16x16x32_f16(Ul[a], Bh, aU[a][t], 0, 0, 0);
        aV[a][t] = __builtin_amdgcn_mfma_f32_16x16x32_f16(Vh[a], Bh, aV[a][t], 0, 0, 0);
        aV[a][t] = __builtin_amdgcn_mfma_f32_16x16x32_f16(Vh[a], Bl, aV[a][t], 0, 0, 0);
        aV[a][t] = __builtin_amdgcn_mfma_f32_16x16x32_f16(Vl[a], Bh, aV[a][t], 0, 0, 0);
      }
    }
  }
#pragma unroll
  for (int a = 0; a < 2; a++)
#pragma unroll
    for (int t = 0; t < 8; t++)
#pragma unroll
      for (int j = 0; j < 4; j++) {
        size_t base = ((size_t)b * 64 + o0 + a * 16 + quad * 4 + j) * NN + nb0 + t * 16 + col;
        Uc[base] = aU[a][t][j];
        Vc[base] = aV[a][t][j];
      }
}

// ---------------- edge aggregation: stats + normalized max-over-k ----------------
// Uc/Vc are chunk-local [b][64][NN]; xo pre-offset to the chunk's first channel.
__global__ __launch_bounds__(256) void edge_kernel(const float* __restrict__ Uc,
    const float* __restrict__ Vc, const int* __restrict__ idx,
    float* __restrict__ xo)
{
  __shared__ float Ur[4 * 2052];   // +4 pad breaks the i-stride bank collision
  __shared__ float red[8][4];
  __shared__ float smv[8];
  const int b = blockIdx.y, o0 = blockIdx.x * 4;
  const int t = threadIdx.x, lane = t & 63, wave = t >> 6;
  for (int r = 0; r < 4; r++)
    for (int i = t; i < NN; i += 256)
      Ur[r * 2052 + i] = Uc[((size_t)b * 64 + o0 + r) * NN + i];
  __syncthreads();
  const float* Vb = Vc + ((size_t)b * 64 + o0) * NN;
  const int* ib = idx + (size_t)b * NN * KK;
  float s0 = 0, s1 = 0, s2 = 0, s3 = 0, c0 = 0, c1 = 0, c2 = 0, c3 = 0;
  for (int n = t; n < NN; n += 256) {
    float v0 = Vb[n], v1 = Vb[NN + n], v2 = Vb[2 * NN + n], v3 = Vb[3 * NN + n];
    const int* ip = ib + (size_t)n * KK;
#pragma unroll
    for (int j = 0; j < KK; j++) {
      int m = ip[j];
      float y0 = Ur[m] + v0, y1 = Ur[2052 + m] + v1;
      float y2 = Ur[4104 + m] + v2, y3 = Ur[6156 + m] + v3;
      s0 += y0; c0 = fmaf(y0, y0, c0);
      s1 += y1; c1 = fmaf(y1, y1, c1);
      s2 += y2; c2 = fmaf(y2, y2, c2);
      s3 += y3; c3 = fmaf(y3, y3, c3);
    }
  }
  float sa[4] = { s0, s1, s2, s3 }, ca[4] = { c0, c1, c2, c3 };
#pragma unroll
  for (int r = 0; r < 4; r++) {
    float a = sa[r], c = ca[r];
#pragma unroll
    for (int d = 1; d < 64; d <<= 1) { a += shflx_f(a, d); c += shflx_f(c, d); }
    if (lane == 0) { red[r][wave] = a; red[4 + r][wave] = c; }
  }
  __syncthreads();
  if (t < 4) {
    float a = red[t][0] + red[t][1] + red[t][2] + red[t][3];
    float c = red[4 + t][0] + red[4 + t][1] + red[4 + t][2] + red[4 + t][3];
    const float inv = 1.f / (float)(NN * KK);
    float mu = a * inv;
    float var = fmaxf(c * inv - mu * mu, 0.f);
    smv[t] = mu;
    smv[4 + t] = rsqrtf(var + EPSF);
  }
  __syncthreads();
  const float mu0 = smv[0], mu1 = smv[1], mu2 = smv[2], mu3 = smv[3];
  const float i0 = smv[4], i1 = smv[5], i2 = smv[6], i3 = smv[7];
  for (int n = t; n < NN; n += 256) {
    float v0 = Vb[n], v1 = Vb[NN + n], v2 = Vb[2 * NN + n], v3 = Vb[3 * NN + n];
    const int* ip = ib + (size_t)n * KK;
    float m0 = -3.4e38f, m1 = m0, m2 = m0, m3 = m0;
#pragma unroll
    for (int j = 0; j < KK; j++) {
      int m = ip[j];
      m0 = fmaxf(m0, Ur[m] + v0);
      m1 = fmaxf(m1, Ur[2052 + m] + v1);
      m2 = fmaxf(m2, Ur[4104 + m] + v2);
      m3 = fmaxf(m3, Ur[6156 + m] + v3);
    }
    float z;  // leaky-relu commutes with max (inv > 0)
    z = (m0 - mu0) * i0; xo[((size_t)b * 512 + o0 + 0) * NN + n] = z >= 0.f ? z : 0.2f * z;
    z = (m1 - mu1) * i1; xo[((size_t)b * 512 + o0 + 1) * NN + n] = z >= 0.f ? z : 0.2f * z;
    z = (m2 - mu2) * i2; xo[((size_t)b * 512 + o0 + 2) * NN + n] = z >= 0.f ? z : 0.2f * z;
    z = (m3 - mu3) * i3; xo[((size_t)b * 512 + o0 + 3) * NN + n] = z >= 0.f ? z : 0.2f * z;
  }
}

__global__ __launch_bounds__(256) void bn5stat_kernel(const float* __restrict__ y5,
    float* __restrict__ bn5) {
  __shared__ float rs[4], rq[4];
  const int o = blockIdx.x, t = threadIdx.x, lane = t & 63, wave = t >> 6;
  float s = 0.f, q = 0.f;
  for (int b = 0; b < NB; b++) {
    const float* p = y5 + ((size_t)b * 512 + o) * NN;
    for (int n = t; n < NN; n += 256) { float v = p[n]; s += v; q = fmaf(v, v, q); }
  }
#pragma unroll
  for (int d = 1; d < 64; d <<= 1) { s += shflx_f(s, d); q += shflx_f(q, d); }
  if (lane == 0) { rs[wave] = s; rq[wave] = q; }
  __syncthreads();
  if (t == 0) {
    float S = rs[0] + rs[1] + rs[2] + rs[3];
    float Q = rq[0] + rq[1] + rq[2] + rq[3];
    const float inv = 1.f / (float)(NB * NN);
    float mu = S * inv;
    float var = fmaxf(Q * inv - mu * mu, 0.f);
    bn5[o] = mu;
    bn5[512 + o] = rsqrtf(var + EPSF);
  }
}

__global__ __launch_bounds__(256) void final_kernel(const float* __restrict__ y5,
    const float* __restrict__ bn5, const float* __restrict__ gamma,
    const float* __restrict__ beta, float* __restrict__ out)
{
  __shared__ float rm[4], rs[4];
  const int o = blockIdx.x, b = blockIdx.y, t = threadIdx.x, lane = t & 63, wave = t >> 6;
  const float mu = bn5[o], iv = bn5[512 + o], g = gamma[o], be = beta[o];
  const float* p = y5 + ((size_t)b * 512 + o) * NN;
  float mx = -3.4e38f, sm = 0.f;
  for (int n = t; n < NN; n += 256) {
    float z = (p[n] - mu) * iv;
    z = z * g + be;
    z = (z >= 0.f) ? z : 0.2f * z;
    mx = fmaxf(mx, z);
    sm += z;
  }
#pragma unroll
  for (int d = 1; d < 64; d <<= 1) { mx = fmaxf(mx, shflx_f(mx, d)); sm += shflx_f(sm, d); }
  if (lane == 0) { rm[wave] = mx; rs[wave] = sm; }
  __syncthreads();
  if (t == 0) {
    float M = fmaxf(fmaxf(rm[0], rm[1]), fmaxf(rm[2], rm[3]));
    float S = rs[0] + rs[1] + rs[2] + rs[3];
    out[(size_t)b * 1024 + o] = M;
    out[(size_t)b * 1024 + 512 + o] = S * (1.f / NN);
  }
}

extern "C" void kernel_launch(void* const* d_in, const int* in_sizes, int n_in,
                              void* d_out, int out_size, void* d_ws, size_t ws_size,
                              hipStream_t stream)
{
  (void)in_sizes; (void)n_in; (void)out_size; (void)ws_size;
  const float* x  = (const float*)d_in[0];
  const float* w1 = (const float*)d_in[1];
  const float* w2 = (const float*)d_in[2];
  const float* w3 = (const float*)d_in[3];
  const float* w4 = (const float*)d_in[4];
  const float* w5 = (const float*)d_in[5];
  const float* g5 = (const float*)d_in[6];
  const float* b5 = (const float*)d_in[7];
  float* out = (float*)d_out;

  // workspace layout (~137 MB, identical total to the round-4 passing layout)
  float* ws   = (float*)d_ws;
  float* xcat = ws;                         // 16*512*2048 fp32 (67.1 MB)
  float* Ub   = xcat + 16777216;            // 16*256*2048 fp32 (33.55 MB)
  float* Vb   = Ub + 8388608;               // 16*256*2048 fp32 (33.55 MB)
  int*   idxb = (int*)(Vb + 8388608);       // 16*2048*20 (2.62 MB)
  float* xxb  = (float*)(idxb + 655360);    // 16*2048
  float* bn5  = xxb + 32768;                // 1024

  // --- Vb internal carve-up (all lifetimes stream-ordered, no overlap in use):
  //   [0        , 2097152 )  xth  (f16 frags hi)        prep->knn2/merge/uv reads
  //   [2097152  , 4194304 )  xtl  (f16 frags lo)
  //   [4194304  , 4259840 )  cntb (survivor counts)
  //   [4259840  , 6356992 )  Vc   (chunk V, 64ch fp32)  uv writes, edge reads
  //   [6356992  , 6422528 )  uv weight f16 stash (4 x 32768 halves max)
  _Float16* xth = (_Float16*)Vb;
  _Float16* xtl = xth + (size_t)NB * NN * 128;
  int* cntb = (int*)(Vb + 4194304);
  float* Vc = Vb + 4259840;
  _Float16* wuh = (_Float16*)(Vb + 6356992);
  _Float16* wul = wuh + 32768;
  _Float16* wvh = wul + 32768;
  _Float16* wvl = wvh + 32768;

  ull* slist = (ull*)Ub;                    // survivor lists alias Ub (dead after merge)
  float* Uc = Ub;                           // chunk U buffer (64ch) also at Ub head

  // y5 stage: w5 frags overwrite idx region (free after edge4); xcf frags reuse
  // Ub+Vb wholesale; y5 fp32 reuses xcat (fully consumed by y5cvt first).
  _Float16* w5h = (_Float16*)idxb;
  _Float16* w5l = w5h + 262144;
  _Float16* xcfh = (_Float16*)Ub;
  _Float16* xcfl = (_Float16*)Vb;
  float* y5 = xcat;

  struct Lyr { const float* xin; long bstride; int C, KB, O, coff; const float* w; };
  const Lyr L[4] = {
    { x,              3L * NN,   3,   1, 64,  0,   w1 },
    { xcat,           512L * NN, 64,  2, 64,  64,  w2 },
    { xcat + 64 * NN, 512L * NN, 64,  2, 128, 128, w3 },
    { xcat + 128 * NN,512L * NN, 128, 4, 256, 256, w4 },
  };

  for (int l = 0; l < 4; l++) {
    const int Cp = L[l].KB * 32, O = L[l].O;
    prep_kernel<<<dim3(NN / 256, NB), 256, 0, stream>>>(L[l].xin, xth, xtl, xxb,
                                                        L[l].C, L[l].KB, L[l].bstride);
    switch (L[l].KB) {
      case 1: knn2<1><<<dim3(NB * 2, NN / 256), 256, 0, stream>>>(xth, xtl, xxb, slist, cntb); break;
      case 2: knn2<2><<<dim3(NB * 2, NN / 256), 256, 0, stream>>>(xth, xtl, xxb, slist, cntb); break;
      default: knn2<4><<<dim3(NB * 2, NN / 256), 256, 0, stream>>>(xth, xtl, xxb, slist, cntb); break;
    }
    knn_merge<<<dim3(NN / 4, NB), 256, 0, stream>>>(slist, cntb, xth, xtl, xxb, idxb,
                                                    Cp, L[l].C);
    wcvt_uv<<<(O * Cp + 255) / 256, 256, 0, stream>>>(L[l].w, wuh, wul, wvh, wvl,
                                                      L[l].C, Cp, O);
    for (int c0 = 0; c0 < O; c0 += 64) {
      uv_mfma<<<dim3(2, NN / 512, NB), 256, 0, stream>>>(
          wuh + (size_t)c0 * Cp, wul + (size_t)c0 * Cp,
          wvh + (size_t)c0 * Cp, wvl + (size_t)c0 * Cp,
          xth, xtl, Uc, Vc, Cp);
      edge_kernel<<<dim3(16, NB), 256, 0, stream>>>(Uc, Vc, idxb,
          xcat + (size_t)(L[l].coff + c0) * NN);
    }
  }
  w5cvt<<<1024, 256, 0, stream>>>(w5, w5h, w5l);
  y5cvt_kernel<<<dim3(NN / 256, NB, 4), 256, 0, stream>>>(xcat, xcfh, xcfl);
  y5_mfma<<<dim3(2, NN / 128, NB), 256, 0, stream>>>(w5h, w5l, xcfh, xcfl, y5);
  bn5stat_kernel<<<512, 256, 0, stream>>>(y5, bn5);
  final_kernel<<<dim3(512, NB), 256, 0, stream>>>(y5, bn5, g5, b5, out);
}